// Round 21
// baseline (212.241 us; speedup 1.0000x reference)
//
#include <hip/hip_runtime.h>
#include <math.h>

#define NN 16384      // B*N total nodes
#define NPB 4096      // nodes per batch
#define KCAP 128      // survivor capacity per query (expected ~30 with guard)
#define TS 512        // kNN candidate tile size
#define GUARD 0.25f   // d2-space guard: >= 2x worst f16-rounding error + trunc slack

typedef __attribute__((ext_vector_type(8))) short short8v;
typedef __attribute__((ext_vector_type(4))) float float4v;
typedef __attribute__((ext_vector_type(2))) _Float16 half2v;

#if defined(__has_builtin)
#if __has_builtin(__builtin_amdgcn_fdot2)
#define HAS_FDOT2 1
#endif
#endif

#ifdef HAS_FDOT2
#define FDOT2(a,b,c) __builtin_amdgcn_fdot2((a),(b),(c),false)
#else
__device__ __forceinline__ float FDOT2(half2v a, half2v b, float c){
  return c + (float)a[0]*(float)b[0] + (float)a[1]*(float)b[1];
}
#endif

__device__ __forceinline__ float gelu_f(float v){
  return 0.5f*v*(1.0f+erff(v*0.70710678118654752440f));
}

// f32 -> bf16 bits, round-to-nearest-even
__device__ __forceinline__ unsigned short f2bf(float v){
  union{float f; unsigned u;} c; c.f = v;
  const unsigned r = c.u + 0x7FFFu + ((c.u >> 16) & 1u);
  return (unsigned short)(r >> 16);
}
__device__ __forceinline__ float bf2f(unsigned short b){
  return __uint_as_float(((unsigned)b) << 16);
}

// monotone float->uint map: order-preserving for all finite values
__device__ __forceinline__ unsigned fmap(float d2){
  unsigned u = __float_as_uint(d2);
  return u ^ ((unsigned)((int)u >> 31) | 0x80000000u);
}

// canonical exact distance key (same expression everywhere -> identical bits)
__device__ __forceinline__ unsigned dkey(const float4 qa, const float4 qb, const float sqn,
                                         const float4 a, const float4 b){
  const float dot = qa.x*a.x + qa.y*a.y + qa.z*a.z + qa.w*a.w + qb.x*b.x + qb.y*b.y;
  const float d2 = sqn + b.z - 2.0f*dot;
  return fmap(d2);
}

// ascending-by-lane bitonic sort of one u64 per lane across the 64-lane wave
__device__ __forceinline__ unsigned long long bsort64(unsigned long long v, int lane){
#pragma unroll
  for (int k=2;k<=64;k<<=1){
#pragma unroll
    for (int j=k>>1;j>0;j>>=1){
      const unsigned long long o = __shfl_xor(v, j);
      const bool keepMin = ((lane & k) == 0) == ((lane & j) == 0);
      const unsigned long long mn = v < o ? v : o;
      const unsigned long long mx = v < o ? o : v;
      v = keepMin ? mn : mx;
    }
  }
  return v;
}

// ascending-by-lane bitonic sort of one u32 per lane
__device__ __forceinline__ unsigned bsort32(unsigned v, int lane){
#pragma unroll
  for (int k=2;k<=64;k<<=1){
#pragma unroll
    for (int j=k>>1;j>0;j>>=1){
      const unsigned o = __shfl_xor(v, j);
      const bool keepMin = ((lane & k) == 0) == ((lane & j) == 0);
      const unsigned mn = v < o ? v : o;
      const unsigned mx = v < o ? o : v;
      v = keepMin ? mn : mx;
    }
  }
  return v;
}

// ---------------- merged prep: blocks 0..63 pack x -> PA/PB/PH; blocks 64.. convert weights ----
__global__ __launch_bounds__(256) void prep_k(const float* __restrict__ x,
                                              float4* __restrict__ PA, float4* __restrict__ PB,
                                              uint4* __restrict__ PH,
                                              const float* __restrict__ W2, const float* __restrict__ W3,
                                              const float* __restrict__ m1W, const float* __restrict__ m2W,
                                              unsigned short* __restrict__ o){
  if (blockIdx.x < NN/256){
    const int n = blockIdx.x*256 + threadIdx.x;
    const float* xr = x + (size_t)n*6;
    const float x0=xr[0],x1=xr[1],x2=xr[2],x3=xr[3],x4=xr[4],x5=xr[5];
    const float sq = x0*x0+x1*x1+x2*x2+x3*x3+x4*x4+x5*x5;
    PA[n] = make_float4(x0,x1,x2,x3);
    PB[n] = make_float4(x4,x5,sq,0.f);
    half2v h01 = {(_Float16)x0, (_Float16)x1};
    half2v h23 = {(_Float16)x2, (_Float16)x3};
    half2v h45 = {(_Float16)x4, (_Float16)x5};
    uint4 ph;
    ph.x = __builtin_bit_cast(unsigned, h01);
    ph.y = __builtin_bit_cast(unsigned, h23);
    ph.z = __builtin_bit_cast(unsigned, h45);
    ph.w = __float_as_uint(sq);
    PH[n] = ph;
  } else {
    const int i = (blockIdx.x - NN/256)*256 + threadIdx.x;   // 122880 total
    float v;
    if (i < 65536)       v = W2[i];
    else if (i < 98304)  v = W3[i-65536];
    else if (i < 114688) v = m1W[i-98304];
    else                 v = m2W[i-114688];
    o[i] = f2bf(v);
  }
}

// ---------------- fat kernel: even blocks = kNN (R19 proven structure);
//                  odd blocks = layer-1 GEMM + fused attention logits.
//                  Independent work co-scheduled so memory-bound gemm waves fill
//                  the latency bubbles of the VALU-bound knn waves. ----------------
__global__ void kng_k(const uint4* __restrict__ PH, const float4* __restrict__ PA,
                      const float4* __restrict__ PB, int* __restrict__ nbr,
                      const float* __restrict__ x, const float* __restrict__ W1,
                      const float* __restrict__ asrc, const float* __restrict__ adst,
                      unsigned short* __restrict__ h,
                      float* __restrict__ als, float* __restrict__ ald){
  __shared__ uint2 C1[2][TS];              // 8 KB {h01,h23}
  __shared__ uint2 C2[2][TS];              // 8 KB {h45,sq}
  __shared__ unsigned skey[4][KCAP];       // 2 KB
  __shared__ unsigned sslot[4][KCAP];      // 2 KB

  if (blockIdx.x & 1){
    // ---- gemm_in6 branch ----
    const int t = (blockIdx.x >> 1)*256 + threadIdx.x;  // over NN*64
    const int n = t >> 6, cg = t & 63;
    const float* xr = x + n*6;
    float xv[6];
#pragma unroll
    for (int d=0; d<6; d++) xv[d] = xr[d];
    float4 acc = make_float4(0.f,0.f,0.f,0.f);
#pragma unroll
    for (int d=0; d<6; d++){
      const float4 wv = *(const float4*)(W1 + d*256 + cg*4);
      acc.x += xv[d]*wv.x; acc.y += xv[d]*wv.y; acc.z += xv[d]*wv.z; acc.w += xv[d]*wv.w;
    }
    ushort4 o;
    o.x = f2bf(acc.x); o.y = f2bf(acc.y); o.z = f2bf(acc.z); o.w = f2bf(acc.w);
    *(ushort4*)(h + (size_t)n*256 + cg*4) = o;

    const int head = cg >> 4;
    const float4 av = *(const float4*)(asrc + head*64 + (cg&15)*4);
    const float4 dv = *(const float4*)(adst + head*64 + (cg&15)*4);
    float s = acc.x*av.x + acc.y*av.y + acc.z*av.z + acc.w*av.w;
    float d = acc.x*dv.x + acc.y*dv.y + acc.z*dv.z + acc.w*dv.w;
#pragma unroll
    for (int off=1; off<16; off<<=1){
      s += __shfl_xor(s, off);
      d += __shfl_xor(d, off);
    }
    if ((cg & 15) == 0){
      als[n*4 + head] = s;
      ald[n*4 + head] = d;
    }
    return;
  }

  // ---- kNN branch ----
  const int t = threadIdx.x, w = t >> 6, lane = t & 63;
  const int n = (blockIdx.x >> 1)*4 + w;
  const int base = n & ~(NPB-1);
  const uint4 qh = PH[n];
  const half2v q01 = __builtin_bit_cast(half2v, qh.x);
  const half2v q23 = __builtin_bit_cast(half2v, qh.y);
  const half2v q45 = __builtin_bit_cast(half2v, qh.z);
  const float sqn = __uint_as_float(qh.w);
  const int selfslot = n - base;

  // stage tile 0
  {
    const uint4 c0 = PH[base + t];
    const uint4 c1 = PH[base + 256 + t];
    C1[0][t]     = make_uint2(c0.x, c0.y);
    C2[0][t]     = make_uint2(c0.z, c0.w);
    C1[0][256+t] = make_uint2(c1.x, c1.y);
    C2[0][256+t] = make_uint2(c1.z, c1.w);
  }
  __syncthreads();

  unsigned kp[32];
  float minf = 3e38f;
#pragma unroll
  for (int tile=0; tile<NPB/TS; ++tile){
    const int buf = tile & 1;
    uint4 n0, n1;
    if (tile < NPB/TS-1){
      n0 = PH[base + (tile+1)*TS + t];
      n1 = PH[base + (tile+1)*TS + 256 + t];
    }
    unsigned lo = 0;
#pragma unroll
    for (int it=0; it<TS/64; ++it){
      const int s = it*64 + lane;
      const uint2 c1 = C1[buf][s];
      const uint2 c2 = C2[buf][s];
      const float dot = FDOT2(q01, __builtin_bit_cast(half2v, c1.x),
                        FDOT2(q23, __builtin_bit_cast(half2v, c1.y),
                        FDOT2(q45, __builtin_bit_cast(half2v, c2.x), 0.f)));
      float d2 = fmaf(-2.f, dot, sqn + __uint_as_float(c2.y));
      d2 = fmaxf(d2, 0.f);
      if (tile*TS + s == selfslot) d2 = 3e38f;   // exclude self
      minf = fminf(minf, d2);
      const unsigned u16 = __float_as_uint(d2) >> 16;   // trunc: monotone for >=0
      if ((it & 1) == 0) lo = u16;
      else               kp[(tile*(TS/64)+it)>>1] = lo | (u16 << 16);
    }
    if (tile < NPB/TS-1){
      C1[buf^1][t]     = make_uint2(n0.x, n0.y);
      C2[buf^1][t]     = make_uint2(n0.z, n0.w);
      C1[buf^1][256+t] = make_uint2(n1.x, n1.y);
      C2[buf^1][256+t] = make_uint2(n1.z, n1.w);
      __syncthreads();
    }
  }

  // pivot: 16th smallest lane-min (floats >=0 -> u32-bit order == float order)
  unsigned T = bsort32(__float_as_uint(minf), lane);
  T = __shfl(T, 15);
  const float TG = __uint_as_float(T) + GUARD;
  const unsigned T16 = __float_as_uint(TG) >> 16;

  // compact survivors (trunc(d2~) <= trunc(TG) -> superset of exact top-16)
  int cnt = 0;
#pragma unroll
  for (int q=0; q<64; ++q){
    const unsigned k16 = (kp[q>>1] >> ((q&1)*16)) & 0xFFFFu;
    const bool p = k16 <= T16;
    const unsigned long long bb = __ballot(p);
    if (p){
      const int pos = cnt + (int)__popcll(bb & ((1ull << lane) - 1ull));
      if (pos < KCAP) sslot[w][pos] = (unsigned)((q>>3)*TS + (q&7)*64 + lane);
    }
    cnt += (int)__popcll(bb);
  }
  if (cnt > KCAP) cnt = KCAP;

  // recompute EXACT keys for survivors (canonical fp32 dkey from global PA/PB)
  for (int i=lane; i<cnt; i+=64){
    const int slot = (int)sslot[w][i];
    const float4 qa = PA[n];
    const float4 qb = PB[n];
    skey[w][i] = dkey(qa, qb, qb.z, PA[base+slot], PB[base+slot]);
  }

  // final: exact top-16 over survivors (u64 = key||slot, ascending, slot tie-break)
  unsigned long long vbest;
  {
    unsigned long long v = ~0ull;
    if (lane < cnt) v = ((unsigned long long)skey[w][lane] << 32) | sslot[w][lane];
    vbest = bsort64(v, lane);
  }
  for (int c=1; c*64 < cnt; ++c){
    const int i = c*64 + lane;
    unsigned long long v = ~0ull;
    if (i < cnt) v = ((unsigned long long)skey[w][i] << 32) | sslot[w][i];
    v = bsort64(v, lane);
    const unsigned long long r = __shfl(v, 63-lane);
    vbest = vbest < r ? vbest : r;
#pragma unroll
    for (int j=32;j>0;j>>=1){
      const unsigned long long o = __shfl_xor(vbest, j);
      const bool keepMin = (lane & j) == 0;
      const unsigned long long mn = vbest < o ? vbest : o;
      const unsigned long long mx = vbest < o ? o : vbest;
      vbest = keepMin ? mn : mx;
    }
  }
  if (lane < 16) nbr[n*16 + lane] = base + (int)(vbest & 0xFFFFFFFFull);
}

// ---------------- GAT aggregation (bf16 gather) -> bf16 output rows;
//                  XCD-swizzled blocks; ALSPLIT sums 2 partial logit slots (layer 3);
//                  RES fuses x@res_W + res_b (layer 3) ----------------
template<int HEADS, int C, bool RES, bool ALSPLIT>
__global__ __launch_bounds__(256) void agg_k(const unsigned short* __restrict__ h,
                                             const float* __restrict__ als, const float* __restrict__ ald,
                                             const int* __restrict__ nbr,
                                             const float* __restrict__ bias, unsigned short* __restrict__ out,
                                             const float* __restrict__ xin, const float* __restrict__ rW,
                                             const float* __restrict__ rb){
  constexpr int CT = HEADS*C;
  constexpr int F  = CT/64;
  const int bid = blockIdx.x;
  const int sbid = (bid & 7)*512 + (bid >> 3);
  const int w = threadIdx.x >> 6, lane = threadIdx.x & 63;
  const int n = sbid*4 + w;
  const int head = (lane*F)/C;
  const int col  = lane*F;
  const int nb = nbr[n*16 + (lane & 15)];
  float aldn;
  if constexpr (ALSPLIT) aldn = ald[n*2] + ald[n*2+1];
  else                   aldn = ald[n*HEADS + head];
  float e[17];
#pragma unroll
  for (int j=0;j<17;j++){
    const int sj = (j<16) ? __shfl(nb, j) : n;
    float v;
    if constexpr (ALSPLIT) v = als[sj*2] + als[sj*2+1] + aldn;
    else                   v = als[sj*HEADS + head] + aldn;
    e[j] = v > 0.f ? v : 0.2f*v;
  }
  float mx = e[0];
#pragma unroll
  for (int j=1;j<17;j++) mx = fmaxf(mx, e[j]);
  float den = 0.f;
#pragma unroll
  for (int j=0;j<17;j++){ e[j] = expf(e[j]-mx); den += e[j]; }
  float acc[F];
#pragma unroll
  for (int f=0;f<F;f++) acc[f]=0.f;
#pragma unroll
  for (int j=0;j<17;j++){
    const int sj = (j<16) ? __shfl(nb, j) : n;
    const unsigned short* hp = h + (size_t)sj*CT + col;
    if constexpr (F==4){
      const ushort4 v = *(const ushort4*)hp;
      acc[0] += e[j]*bf2f(v.x); acc[1] += e[j]*bf2f(v.y);
      acc[2] += e[j]*bf2f(v.z); acc[3] += e[j]*bf2f(v.w);
    } else {
      const ushort2 v = *(const ushort2*)hp;
      acc[0] += e[j]*bf2f(v.x); acc[1] += e[j]*bf2f(v.y);
    }
  }
  const float inv = 1.f/den;
  if constexpr (F==4){
    ushort4 o;
    o.x = f2bf(gelu_f(acc[0]*inv + bias[col+0]));
    o.y = f2bf(gelu_f(acc[1]*inv + bias[col+1]));
    o.z = f2bf(gelu_f(acc[2]*inv + bias[col+2]));
    o.w = f2bf(gelu_f(acc[3]*inv + bias[col+3]));
    *(ushort4*)(out + (size_t)n*CT + col) = o;
  } else {
    float v0 = gelu_f(acc[0]*inv + bias[col+0]);
    float v1 = gelu_f(acc[1]*inv + bias[col+1]);
    if constexpr (RES){
      const float* xr = xin + (size_t)n*6;
      float r0 = rb[col+0], r1 = rb[col+1];
#pragma unroll
      for (int d=0; d<6; d++){
        const float xv = xr[d];
        r0 += xv*rW[d*128 + col+0];
        r1 += xv*rW[d*128 + col+1];
      }
      v0 += r0; v1 += r1;
    }
    ushort2 o;
    o.x = f2bf(v0); o.y = f2bf(v1);
    *(ushort2*)(out + (size_t)n*CT + col) = o;
  }
}

// ---------------- bf16 MFMA GEMM: A[M,KC]bf16 @ B[KC,NC]bf16, BM=128 BN=64 BK=32;
//                  AL emits per-block attention-logit (partial) sums ----------
template<int KC, int NC, bool BIAS, bool GELU, bool OUTBF16, bool AL, int ALH>
__global__ __launch_bounds__(256) void mgemm_k(const unsigned short* __restrict__ A,
                                               const unsigned short* __restrict__ B,
                                               const float* __restrict__ bias, void* __restrict__ Cout,
                                               const float* __restrict__ asrc, const float* __restrict__ adst,
                                               float* __restrict__ als, float* __restrict__ ald){
  __shared__ unsigned short As[4*128*8];   // [g][row][j]
  __shared__ unsigned short Bs[4*64*8];    // [g][n][j]
  const int t = threadIdx.x, wid = t >> 6, lane = t & 63;
  const int r0 = blockIdx.x*128, c0 = blockIdx.y*64;
  const int lg = lane >> 4, l15 = lane & 15;
  float4v acc[2][4];
#pragma unroll
  for (int rf=0;rf<2;rf++)
#pragma unroll
    for (int cf=0;cf<4;cf++)
#pragma unroll
      for (int r=0;r<4;r++) acc[rf][cf][r] = 0.f;

  const int arow = t >> 1, ak0 = (t & 1)*16;
  const int bk = t >> 3, bn0 = (t & 7)*8;

#pragma unroll 1
  for (int kc=0; kc<KC; kc+=32){
    __syncthreads();
    const unsigned short* Ap = A + (size_t)(r0+arow)*KC + kc + ak0;
    const short8v av0 = *(const short8v*)Ap;
    const short8v av1 = *(const short8v*)(Ap + 8);
    *(short8v*)&As[((ak0>>3)+0)*1024 + arow*8] = av0;
    *(short8v*)&As[((ak0>>3)+1)*1024 + arow*8] = av1;
    const unsigned short* Bp = B + (size_t)(kc+bk)*NC + c0 + bn0;
    const short8v bv = *(const short8v*)Bp;
#pragma unroll
    for (int i=0;i<8;i++) Bs[(bk>>3)*512 + (bn0+i)*8 + (bk&7)] = (unsigned short)bv[i];
    __syncthreads();

    short8v af0 = *(const short8v*)&As[lg*1024 + (wid*32 +  0 + l15)*8];
    short8v af1 = *(const short8v*)&As[lg*1024 + (wid*32 + 16 + l15)*8];
    short8v bf[4];
#pragma unroll
    for (int c=0;c<4;c++) bf[c] = *(const short8v*)&Bs[lg*512 + (c*16 + l15)*8];
#pragma unroll
    for (int cf=0;cf<4;cf++){
      acc[0][cf] = __builtin_amdgcn_mfma_f32_16x16x32_bf16(af0, bf[cf], acc[0][cf], 0,0,0);
      acc[1][cf] = __builtin_amdgcn_mfma_f32_16x16x32_bf16(af1, bf[cf], acc[1][cf], 0,0,0);
    }
  }

  // epilogue: D[row=(lane>>4)*4+r][col=lane&15] per frag [measured: m89]
  float av[4], dv[4];
  if constexpr (AL){
#pragma unroll
    for (int cf=0;cf<4;cf++){
      av[cf] = asrc[c0 + cf*16 + l15];
      dv[cf] = adst[c0 + cf*16 + l15];
    }
  }
#pragma unroll
  for (int rf=0;rf<2;rf++)
#pragma unroll
    for (int r=0;r<4;r++){
      const int row = r0 + wid*32 + rf*16 + lg*4 + r;
      float s = 0.f, d = 0.f;
#pragma unroll
      for (int cf=0;cf<4;cf++){
        const int col = c0 + cf*16 + l15;
        float v = acc[rf][cf][r];
        if constexpr (BIAS) v += bias[col];
        if constexpr (GELU) v = gelu_f(v);
        if constexpr (OUTBF16) ((unsigned short*)Cout)[(size_t)row*NC + col] = f2bf(v);
        else                   ((float*)Cout)[(size_t)row*NC + col] = v;
        if constexpr (AL){ s += v*av[cf]; d += v*dv[cf]; }
      }
      if constexpr (AL){
#pragma unroll
        for (int off=1; off<16; off<<=1){
          s += __shfl_xor(s, off);
          d += __shfl_xor(d, off);
        }
        if (l15 == 0){
          als[row*ALH + (c0>>6)] = s;
          ald[row*ALH + (c0>>6)] = d;
        }
      }
    }
}

// ---------------- fused MLP tail: Y2 = gelu(A@m2W + m2b) [128x64 MFMA], then
//                  out = Y2@m3W + m3b computed in-register (per-lane 4-col partials,
//                  16-lane shfl reduce). Y2 quantized to bf16 exactly as before. ----------
__global__ __launch_bounds__(256) void mlp2_k(const unsigned short* __restrict__ A,
                                              const unsigned short* __restrict__ B,
                                              const float* __restrict__ bias2,
                                              const float* __restrict__ W3, const float* __restrict__ b3,
                                              float* __restrict__ out){
  __shared__ unsigned short As[4*128*8];
  __shared__ unsigned short Bs[4*64*8];
  const int t = threadIdx.x, wid = t >> 6, lane = t & 63;
  const int r0 = blockIdx.x*128;
  const int lg = lane >> 4, l15 = lane & 15;
  float4v acc[2][4];
#pragma unroll
  for (int rf=0;rf<2;rf++)
#pragma unroll
    for (int cf=0;cf<4;cf++)
#pragma unroll
      for (int r=0;r<4;r++) acc[rf][cf][r] = 0.f;

  const int arow = t >> 1, ak0 = (t & 1)*16;
  const int bk = t >> 3, bn0 = (t & 7)*8;

#pragma unroll 1
  for (int kc=0; kc<128; kc+=32){
    __syncthreads();
    const unsigned short* Ap = A + (size_t)(r0+arow)*128 + kc + ak0;
    const short8v av0 = *(const short8v*)Ap;
    const short8v av1 = *(const short8v*)(Ap + 8);
    *(short8v*)&As[((ak0>>3)+0)*1024 + arow*8] = av0;
    *(short8v*)&As[((ak0>>3)+1)*1024 + arow*8] = av1;
    const unsigned short* Bp = B + (size_t)(kc+bk)*64 + bn0;
    const short8v bv = *(const short8v*)Bp;
#pragma unroll
    for (int i=0;i<8;i++) Bs[(bk>>3)*512 + (bn0+i)*8 + (bk&7)] = (unsigned short)bv[i];
    __syncthreads();

    short8v af0 = *(const short8v*)&As[lg*1024 + (wid*32 +  0 + l15)*8];
    short8v af1 = *(const short8v*)&As[lg*1024 + (wid*32 + 16 + l15)*8];
    short8v bf[4];
#pragma unroll
    for (int c=0;c<4;c++) bf[c] = *(const short8v*)&Bs[lg*512 + (c*16 + l15)*8];
#pragma unroll
    for (int cf=0;cf<4;cf++){
      acc[0][cf] = __builtin_amdgcn_mfma_f32_16x16x32_bf16(af0, bf[cf], acc[0][cf], 0,0,0);
      acc[1][cf] = __builtin_amdgcn_mfma_f32_16x16x32_bf16(af1, bf[cf], acc[1][cf], 0,0,0);
    }
  }

  // per-lane W3 columns (col = cf*16+l15), bias
  float w3[4][6];
#pragma unroll
  for (int cf=0;cf<4;cf++)
#pragma unroll
    for (int j=0;j<6;j++) w3[cf][j] = W3[(cf*16 + l15)*6 + j];
  float b2l[4];
#pragma unroll
  for (int cf=0;cf<4;cf++) b2l[cf] = bias2[cf*16 + l15];

#pragma unroll
  for (int rf=0;rf<2;rf++)
#pragma unroll
    for (int r=0;r<4;r++){
      const int row = r0 + wid*32 + rf*16 + lg*4 + r;
      float p[6] = {0.f,0.f,0.f,0.f,0.f,0.f};
#pragma unroll
      for (int cf=0;cf<4;cf++){
        float v = gelu_f(acc[rf][cf][r] + b2l[cf]);
        const float vv = bf2f(f2bf(v));   // preserve previous bf16 quantization point
#pragma unroll
        for (int j=0;j<6;j++) p[j] += vv*w3[cf][j];
      }
#pragma unroll
      for (int off=1; off<16; off<<=1)
#pragma unroll
        for (int j=0;j<6;j++) p[j] += __shfl_xor(p[j], off);
      if (l15 == 0){
#pragma unroll
        for (int j=0;j<6;j++) out[(size_t)row*6 + j] = p[j] + b3[j];
      }
    }
}

extern "C" void kernel_launch(void* const* d_in, const int* in_sizes, int n_in,
                              void* d_out, int out_size, void* d_ws, size_t ws_size,
                              hipStream_t stream){
  (void)in_sizes; (void)n_in; (void)out_size; (void)ws_size;
  const float* x      = (const float*)d_in[0];
  const float* W1     = (const float*)d_in[1];
  const float* a_src1 = (const float*)d_in[2];
  const float* a_dst1 = (const float*)d_in[3];
  const float* b1     = (const float*)d_in[4];
  const float* W2     = (const float*)d_in[5];
  const float* a_src2 = (const float*)d_in[6];
  const float* a_dst2 = (const float*)d_in[7];
  const float* b2     = (const float*)d_in[8];
  const float* W3     = (const float*)d_in[9];
  const float* a_src3 = (const float*)d_in[10];
  const float* a_dst3 = (const float*)d_in[11];
  const float* b3     = (const float*)d_in[12];
  const float* res_W  = (const float*)d_in[13];
  const float* res_b  = (const float*)d_in[14];
  const float* m1_W   = (const float*)d_in[15];
  const float* m1_b   = (const float*)d_in[16];
  const float* m2_W   = (const float*)d_in[17];
  const float* m2_b   = (const float*)d_in[18];
  const float* m3_W   = (const float*)d_in[19];
  const float* m3_b   = (const float*)d_in[20];
  float* out = (float*)d_out;

  char* wsb = (char*)d_ws;
  int*            nbr   = (int*)wsb;                                 // 1 MB
  unsigned short* HB256 = (unsigned short*)(wsb + (1u<<20));         // 8 MB bf16 [NN,256]
  unsigned short* YB256 = (unsigned short*)(wsb + (9u<<20));         // 8 MB bf16 [NN,256]
  unsigned short* HB128 = (unsigned short*)(wsb + (17u<<20));        // 4 MB bf16 [NN,128]
  unsigned short* YB128 = (unsigned short*)(wsb + (21u<<20));        // 4 MB bf16 [NN,128]
  unsigned short* HM128 = (unsigned short*)(wsb + (25u<<20));        // 4 MB bf16 [NN,128]
  float*          ALS   = (float*)(wsb + (31u<<20));                 // 256 KB
  float*          ALD   = ALS + NN*4;                                // 256 KB
  float4*         PA    = (float4*)(wsb + (31u<<20) + (512u<<10));   // 256 KB
  float4*         PB    = PA + NN;                                   // 256 KB
  uint4*          PH    = (uint4*)(wsb + (32u<<20));                 // 256 KB
  unsigned short* Wb    = (unsigned short*)(wsb + (32u<<20) + (512u<<10)); // 240 KB
  unsigned short* W2b = Wb;
  unsigned short* W3b = Wb + 65536;
  unsigned short* m1b = Wb + 98304;
  unsigned short* m2b = Wb + 114688;

  prep_k<<<NN/256 + 480, 256, 0, stream>>>(x, PA, PB, PH, W2, W3, m1_W, m2_W, Wb);

  // fat kernel: kNN (even blocks) + layer-1 GEMM/attention-logits (odd blocks)
  kng_k<<<NN/2, 256, 0, stream>>>(PH, PA, PB, nbr, x, W1, a_src1, a_dst1, HB256, ALS, ALD);
  agg_k<4,64,false,false><<<NN/4, 256, 0, stream>>>(HB256, ALS, ALD, nbr, b1, YB256, nullptr, nullptr, nullptr);

  // GAT layer 2: 256 -> 4x64 (attention logits fused into GEMM epilogue)
  mgemm_k<256,256,false,false,true,true,4><<<dim3(128,4), 256, 0, stream>>>(
      YB256, W2b, nullptr, HB256, a_src2, a_dst2, ALS, ALD);
  agg_k<4,64,false,false><<<NN/4, 256, 0, stream>>>(HB256, ALS, ALD, nbr, b2, YB256, nullptr, nullptr, nullptr);

  // GAT layer 3: 256 -> 1x128; split attention logits fused into GEMM epilogue
  mgemm_k<256,128,false,false,true,true,2><<<dim3(128,2), 256, 0, stream>>>(
      YB256, W3b, nullptr, HB128, a_src3, a_dst3, ALS, ALD);
  agg_k<1,128,true,true><<<NN/4, 256, 0, stream>>>(HB128, ALS, ALD, nbr, b3, YB128, x, res_W, res_b);

  // MLP: m1 MFMA, then fused m2+m3
  mgemm_k<128,128,true,true,true,false,1><<<dim3(128,2), 256, 0, stream>>>(
      YB128, m1b, m1_b, HM128, nullptr, nullptr, nullptr, nullptr);
  mlp2_k<<<128, 256, 0, stream>>>(HM128, m2b, m2_b, m3_W, m3_b, out);
}

// Round 22
// 174.962 us; speedup vs baseline: 1.2131x; 1.2131x over previous
//
#include <hip/hip_runtime.h>
#include <math.h>

#define NN 16384      // B*N total nodes
#define NPB 4096      // nodes per batch
#define KCAP 128      // survivor capacity per query (expected ~30 with guard)
#define TS 512        // kNN candidate tile size
#define GUARD 0.25f   // d2-space guard: >= 2x worst f16-rounding error + trunc slack

typedef __attribute__((ext_vector_type(8))) short short8v;
typedef __attribute__((ext_vector_type(4))) float float4v;
typedef __attribute__((ext_vector_type(2))) _Float16 half2v;

#if defined(__has_builtin)
#if __has_builtin(__builtin_amdgcn_fdot2)
#define HAS_FDOT2 1
#endif
#endif

#ifdef HAS_FDOT2
#define FDOT2(a,b,c) __builtin_amdgcn_fdot2((a),(b),(c),false)
#else
__device__ __forceinline__ float FDOT2(half2v a, half2v b, float c){
  return c + (float)a[0]*(float)b[0] + (float)a[1]*(float)b[1];
}
#endif

__device__ __forceinline__ float gelu_f(float v){
  return 0.5f*v*(1.0f+erff(v*0.70710678118654752440f));
}

// f32 -> bf16 bits, round-to-nearest-even
__device__ __forceinline__ unsigned short f2bf(float v){
  union{float f; unsigned u;} c; c.f = v;
  const unsigned r = c.u + 0x7FFFu + ((c.u >> 16) & 1u);
  return (unsigned short)(r >> 16);
}
__device__ __forceinline__ float bf2f(unsigned short b){
  return __uint_as_float(((unsigned)b) << 16);
}

// monotone float->uint map: order-preserving for all finite values
__device__ __forceinline__ unsigned fmap(float d2){
  unsigned u = __float_as_uint(d2);
  return u ^ ((unsigned)((int)u >> 31) | 0x80000000u);
}

// canonical exact distance key (same expression everywhere -> identical bits)
__device__ __forceinline__ unsigned dkey(const float4 qa, const float4 qb, const float sqn,
                                         const float4 a, const float4 b){
  const float dot = qa.x*a.x + qa.y*a.y + qa.z*a.z + qa.w*a.w + qb.x*b.x + qb.y*b.y;
  const float d2 = sqn + b.z - 2.0f*dot;
  return fmap(d2);
}

// ascending-by-lane bitonic sort of one u64 per lane across the 64-lane wave
__device__ __forceinline__ unsigned long long bsort64(unsigned long long v, int lane){
#pragma unroll
  for (int k=2;k<=64;k<<=1){
#pragma unroll
    for (int j=k>>1;j>0;j>>=1){
      const unsigned long long o = __shfl_xor(v, j);
      const bool keepMin = ((lane & k) == 0) == ((lane & j) == 0);
      const unsigned long long mn = v < o ? v : o;
      const unsigned long long mx = v < o ? o : v;
      v = keepMin ? mn : mx;
    }
  }
  return v;
}

// ascending-by-lane bitonic sort of one u32 per lane
__device__ __forceinline__ unsigned bsort32(unsigned v, int lane){
#pragma unroll
  for (int k=2;k<=64;k<<=1){
#pragma unroll
    for (int j=k>>1;j>0;j>>=1){
      const unsigned o = __shfl_xor(v, j);
      const bool keepMin = ((lane & k) == 0) == ((lane & j) == 0);
      const unsigned mn = v < o ? v : o;
      const unsigned mx = v < o ? o : v;
      v = keepMin ? mn : mx;
    }
  }
  return v;
}

// ---------------- merged prep: blocks 0..63 pack x -> PA/PB/PH; blocks 64.. convert weights ----
__global__ __launch_bounds__(256) void prep_k(const float* __restrict__ x,
                                              float4* __restrict__ PA, float4* __restrict__ PB,
                                              uint4* __restrict__ PH,
                                              const float* __restrict__ W2, const float* __restrict__ W3,
                                              const float* __restrict__ m1W, const float* __restrict__ m2W,
                                              unsigned short* __restrict__ o){
  if (blockIdx.x < NN/256){
    const int n = blockIdx.x*256 + threadIdx.x;
    const float* xr = x + (size_t)n*6;
    const float x0=xr[0],x1=xr[1],x2=xr[2],x3=xr[3],x4=xr[4],x5=xr[5];
    const float sq = x0*x0+x1*x1+x2*x2+x3*x3+x4*x4+x5*x5;
    PA[n] = make_float4(x0,x1,x2,x3);
    PB[n] = make_float4(x4,x5,sq,0.f);
    half2v h01 = {(_Float16)x0, (_Float16)x1};
    half2v h23 = {(_Float16)x2, (_Float16)x3};
    half2v h45 = {(_Float16)x4, (_Float16)x5};
    uint4 ph;
    ph.x = __builtin_bit_cast(unsigned, h01);
    ph.y = __builtin_bit_cast(unsigned, h23);
    ph.z = __builtin_bit_cast(unsigned, h45);
    ph.w = __float_as_uint(sq);
    PH[n] = ph;
  } else {
    const int i = (blockIdx.x - NN/256)*256 + threadIdx.x;   // 122880 total
    float v;
    if (i < 65536)       v = W2[i];
    else if (i < 98304)  v = W3[i-65536];
    else if (i < 114688) v = m1W[i-98304];
    else                 v = m2W[i-114688];
    o[i] = f2bf(v);
  }
}

// ---------------- kNN (R19/R20 proven): 1 query/wave, double-buffered LDS tiles,
//                  issue-early loads, one barrier/tile, exact tail ----------------
__global__ void knn_k(const uint4* __restrict__ PH, const float4* __restrict__ PA,
                      const float4* __restrict__ PB, int* __restrict__ nbr){
  __shared__ uint2 C1[2][TS];              // 8 KB {h01,h23}
  __shared__ uint2 C2[2][TS];              // 8 KB {h45,sq}
  __shared__ unsigned skey[4][KCAP];       // 2 KB
  __shared__ unsigned sslot[4][KCAP];      // 2 KB
  const int t = threadIdx.x, w = t >> 6, lane = t & 63;
  const int n = blockIdx.x*4 + w;
  const int base = n & ~(NPB-1);
  const uint4 qh = PH[n];
  const half2v q01 = __builtin_bit_cast(half2v, qh.x);
  const half2v q23 = __builtin_bit_cast(half2v, qh.y);
  const half2v q45 = __builtin_bit_cast(half2v, qh.z);
  const float sqn = __uint_as_float(qh.w);
  const int selfslot = n - base;

  // stage tile 0
  {
    const uint4 c0 = PH[base + t];
    const uint4 c1 = PH[base + 256 + t];
    C1[0][t]     = make_uint2(c0.x, c0.y);
    C2[0][t]     = make_uint2(c0.z, c0.w);
    C1[0][256+t] = make_uint2(c1.x, c1.y);
    C2[0][256+t] = make_uint2(c1.z, c1.w);
  }
  __syncthreads();

  unsigned kp[32];
  float minf = 3e38f;
#pragma unroll
  for (int tile=0; tile<NPB/TS; ++tile){
    const int buf = tile & 1;
    uint4 n0, n1;
    if (tile < NPB/TS-1){
      n0 = PH[base + (tile+1)*TS + t];
      n1 = PH[base + (tile+1)*TS + 256 + t];
    }
    unsigned lo = 0;
#pragma unroll
    for (int it=0; it<TS/64; ++it){
      const int s = it*64 + lane;
      const uint2 c1 = C1[buf][s];
      const uint2 c2 = C2[buf][s];
      const float dot = FDOT2(q01, __builtin_bit_cast(half2v, c1.x),
                        FDOT2(q23, __builtin_bit_cast(half2v, c1.y),
                        FDOT2(q45, __builtin_bit_cast(half2v, c2.x), 0.f)));
      float d2 = fmaf(-2.f, dot, sqn + __uint_as_float(c2.y));
      d2 = fmaxf(d2, 0.f);
      if (tile*TS + s == selfslot) d2 = 3e38f;   // exclude self
      minf = fminf(minf, d2);
      const unsigned u16 = __float_as_uint(d2) >> 16;   // trunc: monotone for >=0
      if ((it & 1) == 0) lo = u16;
      else               kp[(tile*(TS/64)+it)>>1] = lo | (u16 << 16);
    }
    if (tile < NPB/TS-1){
      C1[buf^1][t]     = make_uint2(n0.x, n0.y);
      C2[buf^1][t]     = make_uint2(n0.z, n0.w);
      C1[buf^1][256+t] = make_uint2(n1.x, n1.y);
      C2[buf^1][256+t] = make_uint2(n1.z, n1.w);
      __syncthreads();
    }
  }

  // pivot: 16th smallest lane-min (floats >=0 -> u32-bit order == float order)
  unsigned T = bsort32(__float_as_uint(minf), lane);
  T = __shfl(T, 15);
  const float TG = __uint_as_float(T) + GUARD;
  const unsigned T16 = __float_as_uint(TG) >> 16;

  // compact survivors (trunc(d2~) <= trunc(TG) -> superset of exact top-16)
  int cnt = 0;
#pragma unroll
  for (int q=0; q<64; ++q){
    const unsigned k16 = (kp[q>>1] >> ((q&1)*16)) & 0xFFFFu;
    const bool p = k16 <= T16;
    const unsigned long long bb = __ballot(p);
    if (p){
      const int pos = cnt + (int)__popcll(bb & ((1ull << lane) - 1ull));
      if (pos < KCAP) sslot[w][pos] = (unsigned)((q>>3)*TS + (q&7)*64 + lane);
    }
    cnt += (int)__popcll(bb);
  }
  if (cnt > KCAP) cnt = KCAP;

  // recompute EXACT keys for survivors (canonical fp32 dkey from global PA/PB)
  for (int i=lane; i<cnt; i+=64){
    const int slot = (int)sslot[w][i];
    const float4 qa = PA[n];
    const float4 qb = PB[n];
    skey[w][i] = dkey(qa, qb, qb.z, PA[base+slot], PB[base+slot]);
  }

  // final: exact top-16 over survivors (u64 = key||slot, ascending, slot tie-break)
  unsigned long long vbest;
  {
    unsigned long long v = ~0ull;
    if (lane < cnt) v = ((unsigned long long)skey[w][lane] << 32) | sslot[w][lane];
    vbest = bsort64(v, lane);
  }
  for (int c=1; c*64 < cnt; ++c){
    const int i = c*64 + lane;
    unsigned long long v = ~0ull;
    if (i < cnt) v = ((unsigned long long)skey[w][i] << 32) | sslot[w][i];
    v = bsort64(v, lane);
    const unsigned long long r = __shfl(v, 63-lane);
    vbest = vbest < r ? vbest : r;
#pragma unroll
    for (int j=32;j>0;j>>=1){
      const unsigned long long o = __shfl_xor(vbest, j);
      const bool keepMin = (lane & j) == 0;
      const unsigned long long mn = vbest < o ? vbest : o;
      const unsigned long long mx = vbest < o ? o : vbest;
      vbest = keepMin ? mn : mx;
    }
  }
  if (lane < 16) nbr[n*16 + lane] = base + (int)(vbest & 0xFFFFFFFFull);
}

// ---------------- layer-1 GEMM + fused attention logits -> bf16 H ----------------
__global__ __launch_bounds__(256) void gemm_in6(const float* __restrict__ x, const float* __restrict__ W,
                                                const float* __restrict__ asrc, const float* __restrict__ adst,
                                                unsigned short* __restrict__ h,
                                                float* __restrict__ als, float* __restrict__ ald){
  const int t = blockIdx.x*256 + threadIdx.x;  // over NN*64
  const int n = t >> 6, cg = t & 63;
  const float* xr = x + n*6;
  float xv[6];
#pragma unroll
  for (int d=0; d<6; d++) xv[d] = xr[d];
  float4 acc = make_float4(0.f,0.f,0.f,0.f);
#pragma unroll
  for (int d=0; d<6; d++){
    const float4 wv = *(const float4*)(W + d*256 + cg*4);
    acc.x += xv[d]*wv.x; acc.y += xv[d]*wv.y; acc.z += xv[d]*wv.z; acc.w += xv[d]*wv.w;
  }
  ushort4 o;
  o.x = f2bf(acc.x); o.y = f2bf(acc.y); o.z = f2bf(acc.z); o.w = f2bf(acc.w);
  *(ushort4*)(h + (size_t)n*256 + cg*4) = o;

  const int head = cg >> 4;
  const float4 av = *(const float4*)(asrc + head*64 + (cg&15)*4);
  const float4 dv = *(const float4*)(adst + head*64 + (cg&15)*4);
  float s = acc.x*av.x + acc.y*av.y + acc.z*av.z + acc.w*av.w;
  float d = acc.x*dv.x + acc.y*dv.y + acc.z*dv.z + acc.w*dv.w;
#pragma unroll
  for (int off=1; off<16; off<<=1){
    s += __shfl_xor(s, off);
    d += __shfl_xor(d, off);
  }
  if ((cg & 15) == 0){
    als[n*4 + head] = s;
    ald[n*4 + head] = d;
  }
}

// ---------------- GAT aggregation (bf16 gather) -> bf16 output rows;
//                  XCD-swizzled blocks; ALSPLIT sums 2 partial logit slots (layer 3);
//                  RES fuses x@res_W + res_b (layer 3) ----------------
template<int HEADS, int C, bool RES, bool ALSPLIT>
__global__ __launch_bounds__(256) void agg_k(const unsigned short* __restrict__ h,
                                             const float* __restrict__ als, const float* __restrict__ ald,
                                             const int* __restrict__ nbr,
                                             const float* __restrict__ bias, unsigned short* __restrict__ out,
                                             const float* __restrict__ xin, const float* __restrict__ rW,
                                             const float* __restrict__ rb){
  constexpr int CT = HEADS*C;
  constexpr int F  = CT/64;
  const int bid = blockIdx.x;
  const int sbid = (bid & 7)*512 + (bid >> 3);
  const int w = threadIdx.x >> 6, lane = threadIdx.x & 63;
  const int n = sbid*4 + w;
  const int head = (lane*F)/C;
  const int col  = lane*F;
  const int nb = nbr[n*16 + (lane & 15)];
  float aldn;
  if constexpr (ALSPLIT) aldn = ald[n*2] + ald[n*2+1];
  else                   aldn = ald[n*HEADS + head];
  float e[17];
#pragma unroll
  for (int j=0;j<17;j++){
    const int sj = (j<16) ? __shfl(nb, j) : n;
    float v;
    if constexpr (ALSPLIT) v = als[sj*2] + als[sj*2+1] + aldn;
    else                   v = als[sj*HEADS + head] + aldn;
    e[j] = v > 0.f ? v : 0.2f*v;
  }
  float mx = e[0];
#pragma unroll
  for (int j=1;j<17;j++) mx = fmaxf(mx, e[j]);
  float den = 0.f;
#pragma unroll
  for (int j=0;j<17;j++){ e[j] = expf(e[j]-mx); den += e[j]; }
  float acc[F];
#pragma unroll
  for (int f=0;f<F;f++) acc[f]=0.f;
#pragma unroll
  for (int j=0;j<17;j++){
    const int sj = (j<16) ? __shfl(nb, j) : n;
    const unsigned short* hp = h + (size_t)sj*CT + col;
    if constexpr (F==4){
      const ushort4 v = *(const ushort4*)hp;
      acc[0] += e[j]*bf2f(v.x); acc[1] += e[j]*bf2f(v.y);
      acc[2] += e[j]*bf2f(v.z); acc[3] += e[j]*bf2f(v.w);
    } else {
      const ushort2 v = *(const ushort2*)hp;
      acc[0] += e[j]*bf2f(v.x); acc[1] += e[j]*bf2f(v.y);
    }
  }
  const float inv = 1.f/den;
  if constexpr (F==4){
    ushort4 o;
    o.x = f2bf(gelu_f(acc[0]*inv + bias[col+0]));
    o.y = f2bf(gelu_f(acc[1]*inv + bias[col+1]));
    o.z = f2bf(gelu_f(acc[2]*inv + bias[col+2]));
    o.w = f2bf(gelu_f(acc[3]*inv + bias[col+3]));
    *(ushort4*)(out + (size_t)n*CT + col) = o;
  } else {
    float v0 = gelu_f(acc[0]*inv + bias[col+0]);
    float v1 = gelu_f(acc[1]*inv + bias[col+1]);
    if constexpr (RES){
      const float* xr = xin + (size_t)n*6;
      float r0 = rb[col+0], r1 = rb[col+1];
#pragma unroll
      for (int d=0; d<6; d++){
        const float xv = xr[d];
        r0 += xv*rW[d*128 + col+0];
        r1 += xv*rW[d*128 + col+1];
      }
      v0 += r0; v1 += r1;
    }
    ushort2 o;
    o.x = f2bf(v0); o.y = f2bf(v1);
    *(ushort2*)(out + (size_t)n*CT + col) = o;
  }
}

// ---------------- bf16 MFMA GEMM: A[M,KC]bf16 @ B[KC,NC]bf16, BM=128 BN=64 BK=32;
//                  AL emits per-block attention-logit (partial) sums ----------
template<int KC, int NC, bool BIAS, bool GELU, bool OUTBF16, bool AL, int ALH>
__global__ __launch_bounds__(256) void mgemm_k(const unsigned short* __restrict__ A,
                                               const unsigned short* __restrict__ B,
                                               const float* __restrict__ bias, void* __restrict__ Cout,
                                               const float* __restrict__ asrc, const float* __restrict__ adst,
                                               float* __restrict__ als, float* __restrict__ ald){
  __shared__ unsigned short As[4*128*8];   // [g][row][j]
  __shared__ unsigned short Bs[4*64*8];    // [g][n][j]
  const int t = threadIdx.x, wid = t >> 6, lane = t & 63;
  const int r0 = blockIdx.x*128, c0 = blockIdx.y*64;
  const int lg = lane >> 4, l15 = lane & 15;
  float4v acc[2][4];
#pragma unroll
  for (int rf=0;rf<2;rf++)
#pragma unroll
    for (int cf=0;cf<4;cf++)
#pragma unroll
      for (int r=0;r<4;r++) acc[rf][cf][r] = 0.f;

  const int arow = t >> 1, ak0 = (t & 1)*16;
  const int bk = t >> 3, bn0 = (t & 7)*8;

#pragma unroll 1
  for (int kc=0; kc<KC; kc+=32){
    __syncthreads();
    const unsigned short* Ap = A + (size_t)(r0+arow)*KC + kc + ak0;
    const short8v av0 = *(const short8v*)Ap;
    const short8v av1 = *(const short8v*)(Ap + 8);
    *(short8v*)&As[((ak0>>3)+0)*1024 + arow*8] = av0;
    *(short8v*)&As[((ak0>>3)+1)*1024 + arow*8] = av1;
    const unsigned short* Bp = B + (size_t)(kc+bk)*NC + c0 + bn0;
    const short8v bv = *(const short8v*)Bp;
#pragma unroll
    for (int i=0;i<8;i++) Bs[(bk>>3)*512 + (bn0+i)*8 + (bk&7)] = (unsigned short)bv[i];
    __syncthreads();

    short8v af0 = *(const short8v*)&As[lg*1024 + (wid*32 +  0 + l15)*8];
    short8v af1 = *(const short8v*)&As[lg*1024 + (wid*32 + 16 + l15)*8];
    short8v bf[4];
#pragma unroll
    for (int c=0;c<4;c++) bf[c] = *(const short8v*)&Bs[lg*512 + (c*16 + l15)*8];
#pragma unroll
    for (int cf=0;cf<4;cf++){
      acc[0][cf] = __builtin_amdgcn_mfma_f32_16x16x32_bf16(af0, bf[cf], acc[0][cf], 0,0,0);
      acc[1][cf] = __builtin_amdgcn_mfma_f32_16x16x32_bf16(af1, bf[cf], acc[1][cf], 0,0,0);
    }
  }

  // epilogue: D[row=(lane>>4)*4+r][col=lane&15] per frag [measured: m89]
  float av[4], dv[4];
  if constexpr (AL){
#pragma unroll
    for (int cf=0;cf<4;cf++){
      av[cf] = asrc[c0 + cf*16 + l15];
      dv[cf] = adst[c0 + cf*16 + l15];
    }
  }
#pragma unroll
  for (int rf=0;rf<2;rf++)
#pragma unroll
    for (int r=0;r<4;r++){
      const int row = r0 + wid*32 + rf*16 + lg*4 + r;
      float s = 0.f, d = 0.f;
#pragma unroll
      for (int cf=0;cf<4;cf++){
        const int col = c0 + cf*16 + l15;
        float v = acc[rf][cf][r];
        if constexpr (BIAS) v += bias[col];
        if constexpr (GELU) v = gelu_f(v);
        if constexpr (OUTBF16) ((unsigned short*)Cout)[(size_t)row*NC + col] = f2bf(v);
        else                   ((float*)Cout)[(size_t)row*NC + col] = v;
        if constexpr (AL){ s += v*av[cf]; d += v*dv[cf]; }
      }
      if constexpr (AL){
#pragma unroll
        for (int off=1; off<16; off<<=1){
          s += __shfl_xor(s, off);
          d += __shfl_xor(d, off);
        }
        if (l15 == 0){
          als[row*ALH + (c0>>6)] = s;
          ald[row*ALH + (c0>>6)] = d;
        }
      }
    }
}

// ---------------- fused MLP tail: Y2 = gelu(A@m2W + m2b) [128x64 MFMA], then
//                  out = Y2@m3W + m3b in-register (per-lane partials, 16-lane reduce) ----
__global__ __launch_bounds__(256) void mlp2_k(const unsigned short* __restrict__ A,
                                              const unsigned short* __restrict__ B,
                                              const float* __restrict__ bias2,
                                              const float* __restrict__ W3, const float* __restrict__ b3,
                                              float* __restrict__ out){
  __shared__ unsigned short As[4*128*8];
  __shared__ unsigned short Bs[4*64*8];
  const int t = threadIdx.x, wid = t >> 6, lane = t & 63;
  const int r0 = blockIdx.x*128;
  const int lg = lane >> 4, l15 = lane & 15;
  float4v acc[2][4];
#pragma unroll
  for (int rf=0;rf<2;rf++)
#pragma unroll
    for (int cf=0;cf<4;cf++)
#pragma unroll
      for (int r=0;r<4;r++) acc[rf][cf][r] = 0.f;

  const int arow = t >> 1, ak0 = (t & 1)*16;
  const int bk = t >> 3, bn0 = (t & 7)*8;

#pragma unroll 1
  for (int kc=0; kc<128; kc+=32){
    __syncthreads();
    const unsigned short* Ap = A + (size_t)(r0+arow)*128 + kc + ak0;
    const short8v av0 = *(const short8v*)Ap;
    const short8v av1 = *(const short8v*)(Ap + 8);
    *(short8v*)&As[((ak0>>3)+0)*1024 + arow*8] = av0;
    *(short8v*)&As[((ak0>>3)+1)*1024 + arow*8] = av1;
    const unsigned short* Bp = B + (size_t)(kc+bk)*64 + bn0;
    const short8v bv = *(const short8v*)Bp;
#pragma unroll
    for (int i=0;i<8;i++) Bs[(bk>>3)*512 + (bn0+i)*8 + (bk&7)] = (unsigned short)bv[i];
    __syncthreads();

    short8v af0 = *(const short8v*)&As[lg*1024 + (wid*32 +  0 + l15)*8];
    short8v af1 = *(const short8v*)&As[lg*1024 + (wid*32 + 16 + l15)*8];
    short8v bf[4];
#pragma unroll
    for (int c=0;c<4;c++) bf[c] = *(const short8v*)&Bs[lg*512 + (c*16 + l15)*8];
#pragma unroll
    for (int cf=0;cf<4;cf++){
      acc[0][cf] = __builtin_amdgcn_mfma_f32_16x16x32_bf16(af0, bf[cf], acc[0][cf], 0,0,0);
      acc[1][cf] = __builtin_amdgcn_mfma_f32_16x16x32_bf16(af1, bf[cf], acc[1][cf], 0,0,0);
    }
  }

  // per-lane W3 columns (col = cf*16+l15), bias
  float w3[4][6];
#pragma unroll
  for (int cf=0;cf<4;cf++)
#pragma unroll
    for (int j=0;j<6;j++) w3[cf][j] = W3[(cf*16 + l15)*6 + j];
  float b2l[4];
#pragma unroll
  for (int cf=0;cf<4;cf++) b2l[cf] = bias2[cf*16 + l15];

#pragma unroll
  for (int rf=0;rf<2;rf++)
#pragma unroll
    for (int r=0;r<4;r++){
      const int row = r0 + wid*32 + rf*16 + lg*4 + r;
      float p[6] = {0.f,0.f,0.f,0.f,0.f,0.f};
#pragma unroll
      for (int cf=0;cf<4;cf++){
        float v = gelu_f(acc[rf][cf][r] + b2l[cf]);
        const float vv = bf2f(f2bf(v));   // preserve previous bf16 quantization point
#pragma unroll
        for (int j=0;j<6;j++) p[j] += vv*w3[cf][j];
      }
#pragma unroll
      for (int off=1; off<16; off<<=1)
#pragma unroll
        for (int j=0;j<6;j++) p[j] += __shfl_xor(p[j], off);
      if (l15 == 0){
#pragma unroll
        for (int j=0;j<6;j++) out[(size_t)row*6 + j] = p[j] + b3[j];
      }
    }
}

extern "C" void kernel_launch(void* const* d_in, const int* in_sizes, int n_in,
                              void* d_out, int out_size, void* d_ws, size_t ws_size,
                              hipStream_t stream){
  (void)in_sizes; (void)n_in; (void)out_size; (void)ws_size;
  const float* x      = (const float*)d_in[0];
  const float* W1     = (const float*)d_in[1];
  const float* a_src1 = (const float*)d_in[2];
  const float* a_dst1 = (const float*)d_in[3];
  const float* b1     = (const float*)d_in[4];
  const float* W2     = (const float*)d_in[5];
  const float* a_src2 = (const float*)d_in[6];
  const float* a_dst2 = (const float*)d_in[7];
  const float* b2     = (const float*)d_in[8];
  const float* W3     = (const float*)d_in[9];
  const float* a_src3 = (const float*)d_in[10];
  const float* a_dst3 = (const float*)d_in[11];
  const float* b3     = (const float*)d_in[12];
  const float* res_W  = (const float*)d_in[13];
  const float* res_b  = (const float*)d_in[14];
  const float* m1_W   = (const float*)d_in[15];
  const float* m1_b   = (const float*)d_in[16];
  const float* m2_W   = (const float*)d_in[17];
  const float* m2_b   = (const float*)d_in[18];
  const float* m3_W   = (const float*)d_in[19];
  const float* m3_b   = (const float*)d_in[20];
  float* out = (float*)d_out;

  char* wsb = (char*)d_ws;
  int*            nbr   = (int*)wsb;                                 // 1 MB
  unsigned short* HB256 = (unsigned short*)(wsb + (1u<<20));         // 8 MB bf16 [NN,256]
  unsigned short* YB256 = (unsigned short*)(wsb + (9u<<20));         // 8 MB bf16 [NN,256]
  unsigned short* HB128 = (unsigned short*)(wsb + (17u<<20));        // 4 MB bf16 [NN,128]
  unsigned short* YB128 = (unsigned short*)(wsb + (21u<<20));        // 4 MB bf16 [NN,128]
  unsigned short* HM128 = (unsigned short*)(wsb + (25u<<20));        // 4 MB bf16 [NN,128]
  float*          ALS   = (float*)(wsb + (31u<<20));                 // 256 KB
  float*          ALD   = ALS + NN*4;                                // 256 KB
  float4*         PA    = (float4*)(wsb + (31u<<20) + (512u<<10));   // 256 KB
  float4*         PB    = PA + NN;                                   // 256 KB
  uint4*          PH    = (uint4*)(wsb + (32u<<20));                 // 256 KB
  unsigned short* Wb    = (unsigned short*)(wsb + (32u<<20) + (512u<<10)); // 240 KB
  unsigned short* W2b = Wb;
  unsigned short* W3b = Wb + 65536;
  unsigned short* m1b = Wb + 98304;
  unsigned short* m2b = Wb + 114688;

  prep_k<<<NN/256 + 480, 256, 0, stream>>>(x, PA, PB, PH, W2, W3, m1_W, m2_W, Wb);
  knn_k<<<NN/4, 256, 0, stream>>>(PH, PA, PB, nbr);

  // GAT layer 1: 6 -> 4x64 (al fused into GEMM), bf16 H
  gemm_in6<<<NN/4, 256, 0, stream>>>(x, W1, a_src1, a_dst1, HB256, ALS, ALD);
  agg_k<4,64,false,false><<<NN/4, 256, 0, stream>>>(HB256, ALS, ALD, nbr, b1, YB256, nullptr, nullptr, nullptr);

  // GAT layer 2: 256 -> 4x64 (attention logits fused into GEMM epilogue)
  mgemm_k<256,256,false,false,true,true,4><<<dim3(128,4), 256, 0, stream>>>(
      YB256, W2b, nullptr, HB256, a_src2, a_dst2, ALS, ALD);
  agg_k<4,64,false,false><<<NN/4, 256, 0, stream>>>(HB256, ALS, ALD, nbr, b2, YB256, nullptr, nullptr, nullptr);

  // GAT layer 3: 256 -> 1x128; split attention logits fused into GEMM epilogue
  mgemm_k<256,128,false,false,true,true,2><<<dim3(128,2), 256, 0, stream>>>(
      YB256, W3b, nullptr, HB128, a_src3, a_dst3, ALS, ALD);
  agg_k<1,128,true,true><<<NN/4, 256, 0, stream>>>(HB128, ALS, ALD, nbr, b3, YB128, x, res_W, res_b);

  // MLP: m1 MFMA, then fused m2+m3
  mgemm_k<128,128,true,true,true,false,1><<<dim3(128,2), 256, 0, stream>>>(
      YB128, m1b, m1_b, HM128, nullptr, nullptr, nullptr, nullptr);
  mlp2_k<<<128, 256, 0, stream>>>(HM128, m2b, m2_b, m3_W, m3_b, out);
}

// Round 23
// 174.158 us; speedup vs baseline: 1.2187x; 1.0046x over previous
//
#include <hip/hip_runtime.h>
#include <math.h>

#define NN 16384      // B*N total nodes
#define NPB 4096      // nodes per batch
#define KCAP 128      // survivor capacity per query (expected ~30 with guard)
#define TS 1024       // kNN candidate tile size (4 tiles -> 3 in-loop barriers)
#define GUARD 0.25f   // d2-space guard: >= 2x worst f16-rounding error + trunc slack

typedef __attribute__((ext_vector_type(8))) short short8v;
typedef __attribute__((ext_vector_type(4))) float float4v;
typedef __attribute__((ext_vector_type(2))) _Float16 half2v;

#if defined(__has_builtin)
#if __has_builtin(__builtin_amdgcn_fdot2)
#define HAS_FDOT2 1
#endif
#endif

#ifdef HAS_FDOT2
#define FDOT2(a,b,c) __builtin_amdgcn_fdot2((a),(b),(c),false)
#else
__device__ __forceinline__ float FDOT2(half2v a, half2v b, float c){
  return c + (float)a[0]*(float)b[0] + (float)a[1]*(float)b[1];
}
#endif

__device__ __forceinline__ float gelu_f(float v){
  return 0.5f*v*(1.0f+erff(v*0.70710678118654752440f));
}

// f32 -> bf16 bits, round-to-nearest-even
__device__ __forceinline__ unsigned short f2bf(float v){
  union{float f; unsigned u;} c; c.f = v;
  const unsigned r = c.u + 0x7FFFu + ((c.u >> 16) & 1u);
  return (unsigned short)(r >> 16);
}
__device__ __forceinline__ float bf2f(unsigned short b){
  return __uint_as_float(((unsigned)b) << 16);
}

// monotone float->uint map: order-preserving for all finite values
__device__ __forceinline__ unsigned fmap(float d2){
  unsigned u = __float_as_uint(d2);
  return u ^ ((unsigned)((int)u >> 31) | 0x80000000u);
}

// canonical exact distance key (same expression everywhere -> identical bits)
__device__ __forceinline__ unsigned dkey(const float4 qa, const float4 qb, const float sqn,
                                         const float4 a, const float4 b){
  const float dot = qa.x*a.x + qa.y*a.y + qa.z*a.z + qa.w*a.w + qb.x*b.x + qb.y*b.y;
  const float d2 = sqn + b.z - 2.0f*dot;
  return fmap(d2);
}

// ascending-by-lane bitonic sort of one u64 per lane across the 64-lane wave
__device__ __forceinline__ unsigned long long bsort64(unsigned long long v, int lane){
#pragma unroll
  for (int k=2;k<=64;k<<=1){
#pragma unroll
    for (int j=k>>1;j>0;j>>=1){
      const unsigned long long o = __shfl_xor(v, j);
      const bool keepMin = ((lane & k) == 0) == ((lane & j) == 0);
      const unsigned long long mn = v < o ? v : o;
      const unsigned long long mx = v < o ? o : v;
      v = keepMin ? mn : mx;
    }
  }
  return v;
}

// ascending-by-lane bitonic sort of one u32 per lane
__device__ __forceinline__ unsigned bsort32(unsigned v, int lane){
#pragma unroll
  for (int k=2;k<=64;k<<=1){
#pragma unroll
    for (int j=k>>1;j>0;j>>=1){
      const unsigned o = __shfl_xor(v, j);
      const bool keepMin = ((lane & k) == 0) == ((lane & j) == 0);
      const unsigned mn = v < o ? v : o;
      const unsigned mx = v < o ? o : v;
      v = keepMin ? mn : mx;
    }
  }
  return v;
}

// ---------------- merged prep: blocks 0..63 pack x -> PA/PB/PH; blocks 64.. convert weights ----
__global__ __launch_bounds__(256) void prep_k(const float* __restrict__ x,
                                              float4* __restrict__ PA, float4* __restrict__ PB,
                                              uint4* __restrict__ PH,
                                              const float* __restrict__ W2, const float* __restrict__ W3,
                                              const float* __restrict__ m1W, const float* __restrict__ m2W,
                                              unsigned short* __restrict__ o){
  if (blockIdx.x < NN/256){
    const int n = blockIdx.x*256 + threadIdx.x;
    const float* xr = x + (size_t)n*6;
    const float x0=xr[0],x1=xr[1],x2=xr[2],x3=xr[3],x4=xr[4],x5=xr[5];
    const float sq = x0*x0+x1*x1+x2*x2+x3*x3+x4*x4+x5*x5;
    PA[n] = make_float4(x0,x1,x2,x3);
    PB[n] = make_float4(x4,x5,sq,0.f);
    half2v h01 = {(_Float16)x0, (_Float16)x1};
    half2v h23 = {(_Float16)x2, (_Float16)x3};
    half2v h45 = {(_Float16)x4, (_Float16)x5};
    uint4 ph;
    ph.x = __builtin_bit_cast(unsigned, h01);
    ph.y = __builtin_bit_cast(unsigned, h23);
    ph.z = __builtin_bit_cast(unsigned, h45);
    ph.w = __float_as_uint(sq);
    PH[n] = ph;
  } else {
    const int i = (blockIdx.x - NN/256)*256 + threadIdx.x;   // 122880 total
    float v;
    if (i < 65536)       v = W2[i];
    else if (i < 98304)  v = W3[i-65536];
    else if (i < 114688) v = m1W[i-98304];
    else                 v = m2W[i-114688];
    o[i] = f2bf(v);
  }
}

// ---------------- kNN v17: R19 structure with TS=1024 (4 tiles, 3 in-loop barriers).
//                  1 query/wave, double-buffered LDS, issue-early prefetch (4 scalar
//                  uint4 regs — NOT an array, no SROA spill risk), exact tail. ----------
__global__ void knn_k(const uint4* __restrict__ PH, const float4* __restrict__ PA,
                      const float4* __restrict__ PB, int* __restrict__ nbr){
  __shared__ uint2 C1[2][TS];              // 16 KB {h01,h23}
  __shared__ uint2 C2[2][TS];              // 16 KB {h45,sq}
  __shared__ unsigned skey[4][KCAP];       // 2 KB
  __shared__ unsigned sslot[4][KCAP];      // 2 KB
  const int t = threadIdx.x, w = t >> 6, lane = t & 63;
  const int n = blockIdx.x*4 + w;
  const int base = n & ~(NPB-1);
  const uint4 qh = PH[n];
  const half2v q01 = __builtin_bit_cast(half2v, qh.x);
  const half2v q23 = __builtin_bit_cast(half2v, qh.y);
  const half2v q45 = __builtin_bit_cast(half2v, qh.z);
  const float sqn = __uint_as_float(qh.w);
  const int selfslot = n - base;

  // stage tile 0 (1024 entries, 4 per thread)
  {
#pragma unroll
    for (int u=0;u<4;u++){
      const uint4 c = PH[base + u*256 + t];
      C1[0][u*256+t] = make_uint2(c.x, c.y);
      C2[0][u*256+t] = make_uint2(c.z, c.w);
    }
  }
  __syncthreads();

  unsigned kp[32];
  float minf = 3e38f;
#pragma unroll
  for (int tile=0; tile<NPB/TS; ++tile){
    const int buf = tile & 1;
    // issue next tile's global loads BEFORE compute (latency hides under distance loop)
    uint4 n0, n1, n2, n3;
    if (tile < NPB/TS-1){
      n0 = PH[base + (tile+1)*TS +   0 + t];
      n1 = PH[base + (tile+1)*TS + 256 + t];
      n2 = PH[base + (tile+1)*TS + 512 + t];
      n3 = PH[base + (tile+1)*TS + 768 + t];
    }
    unsigned lo = 0;
#pragma unroll
    for (int it=0; it<TS/64; ++it){
      const int s = it*64 + lane;
      const uint2 c1 = C1[buf][s];
      const uint2 c2 = C2[buf][s];
      const float dot = FDOT2(q01, __builtin_bit_cast(half2v, c1.x),
                        FDOT2(q23, __builtin_bit_cast(half2v, c1.y),
                        FDOT2(q45, __builtin_bit_cast(half2v, c2.x), 0.f)));
      float d2 = fmaf(-2.f, dot, sqn + __uint_as_float(c2.y));
      d2 = fmaxf(d2, 0.f);
      if (tile*TS + s == selfslot) d2 = 3e38f;   // exclude self
      minf = fminf(minf, d2);
      const unsigned u16 = __float_as_uint(d2) >> 16;   // trunc: monotone for >=0
      if ((it & 1) == 0) lo = u16;
      else               kp[(tile*(TS/64)+it)>>1] = lo | (u16 << 16);
    }
    if (tile < NPB/TS-1){
      C1[buf^1][      t] = make_uint2(n0.x, n0.y);
      C2[buf^1][      t] = make_uint2(n0.z, n0.w);
      C1[buf^1][256 + t] = make_uint2(n1.x, n1.y);
      C2[buf^1][256 + t] = make_uint2(n1.z, n1.w);
      C1[buf^1][512 + t] = make_uint2(n2.x, n2.y);
      C2[buf^1][512 + t] = make_uint2(n2.z, n2.w);
      C1[buf^1][768 + t] = make_uint2(n3.x, n3.y);
      C2[buf^1][768 + t] = make_uint2(n3.z, n3.w);
      __syncthreads();
    }
  }

  // pivot: 16th smallest lane-min (floats >=0 -> u32-bit order == float order)
  unsigned T = bsort32(__float_as_uint(minf), lane);
  T = __shfl(T, 15);
  const float TG = __uint_as_float(T) + GUARD;
  const unsigned T16 = __float_as_uint(TG) >> 16;

  // compact survivors (trunc(d2~) <= trunc(TG) -> superset of exact top-16)
  // q = tile*16 + it (16 its/tile at TS=1024); slot = (q>>4)*TS + (q&15)*64 + lane
  int cnt = 0;
#pragma unroll
  for (int q=0; q<64; ++q){
    const unsigned k16 = (kp[q>>1] >> ((q&1)*16)) & 0xFFFFu;
    const bool p = k16 <= T16;
    const unsigned long long bb = __ballot(p);
    if (p){
      const int pos = cnt + (int)__popcll(bb & ((1ull << lane) - 1ull));
      if (pos < KCAP) sslot[w][pos] = (unsigned)((q>>4)*TS + (q&15)*64 + lane);
    }
    cnt += (int)__popcll(bb);
  }
  if (cnt > KCAP) cnt = KCAP;

  // recompute EXACT keys for survivors (canonical fp32 dkey from global PA/PB)
  for (int i=lane; i<cnt; i+=64){
    const int slot = (int)sslot[w][i];
    const float4 qa = PA[n];
    const float4 qb = PB[n];
    skey[w][i] = dkey(qa, qb, qb.z, PA[base+slot], PB[base+slot]);
  }

  // final: exact top-16 over survivors (u64 = key||slot, ascending, slot tie-break)
  unsigned long long vbest;
  {
    unsigned long long v = ~0ull;
    if (lane < cnt) v = ((unsigned long long)skey[w][lane] << 32) | sslot[w][lane];
    vbest = bsort64(v, lane);
  }
  for (int c=1; c*64 < cnt; ++c){
    const int i = c*64 + lane;
    unsigned long long v = ~0ull;
    if (i < cnt) v = ((unsigned long long)skey[w][i] << 32) | sslot[w][i];
    v = bsort64(v, lane);
    const unsigned long long r = __shfl(v, 63-lane);
    vbest = vbest < r ? vbest : r;
#pragma unroll
    for (int j=32;j>0;j>>=1){
      const unsigned long long o = __shfl_xor(vbest, j);
      const bool keepMin = (lane & j) == 0;
      const unsigned long long mn = vbest < o ? vbest : o;
      const unsigned long long mx = vbest < o ? o : vbest;
      vbest = keepMin ? mn : mx;
    }
  }
  if (lane < 16) nbr[n*16 + lane] = base + (int)(vbest & 0xFFFFFFFFull);
}

// ---------------- layer-1 GEMM + fused attention logits -> bf16 H ----------------
__global__ __launch_bounds__(256) void gemm_in6(const float* __restrict__ x, const float* __restrict__ W,
                                                const float* __restrict__ asrc, const float* __restrict__ adst,
                                                unsigned short* __restrict__ h,
                                                float* __restrict__ als, float* __restrict__ ald){
  const int t = blockIdx.x*256 + threadIdx.x;  // over NN*64
  const int n = t >> 6, cg = t & 63;
  const float* xr = x + n*6;
  float xv[6];
#pragma unroll
  for (int d=0; d<6; d++) xv[d] = xr[d];
  float4 acc = make_float4(0.f,0.f,0.f,0.f);
#pragma unroll
  for (int d=0; d<6; d++){
    const float4 wv = *(const float4*)(W + d*256 + cg*4);
    acc.x += xv[d]*wv.x; acc.y += xv[d]*wv.y; acc.z += xv[d]*wv.z; acc.w += xv[d]*wv.w;
  }
  ushort4 o;
  o.x = f2bf(acc.x); o.y = f2bf(acc.y); o.z = f2bf(acc.z); o.w = f2bf(acc.w);
  *(ushort4*)(h + (size_t)n*256 + cg*4) = o;

  const int head = cg >> 4;
  const float4 av = *(const float4*)(asrc + head*64 + (cg&15)*4);
  const float4 dv = *(const float4*)(adst + head*64 + (cg&15)*4);
  float s = acc.x*av.x + acc.y*av.y + acc.z*av.z + acc.w*av.w;
  float d = acc.x*dv.x + acc.y*dv.y + acc.z*dv.z + acc.w*dv.w;
#pragma unroll
  for (int off=1; off<16; off<<=1){
    s += __shfl_xor(s, off);
    d += __shfl_xor(d, off);
  }
  if ((cg & 15) == 0){
    als[n*4 + head] = s;
    ald[n*4 + head] = d;
  }
}

// ---------------- GAT aggregation (bf16 gather) -> bf16 output rows;
//                  XCD-swizzled blocks; ALSPLIT sums 2 partial logit slots (layer 3);
//                  RES fuses x@res_W + res_b (layer 3) ----------------
template<int HEADS, int C, bool RES, bool ALSPLIT>
__global__ __launch_bounds__(256) void agg_k(const unsigned short* __restrict__ h,
                                             const float* __restrict__ als, const float* __restrict__ ald,
                                             const int* __restrict__ nbr,
                                             const float* __restrict__ bias, unsigned short* __restrict__ out,
                                             const float* __restrict__ xin, const float* __restrict__ rW,
                                             const float* __restrict__ rb){
  constexpr int CT = HEADS*C;
  constexpr int F  = CT/64;
  const int bid = blockIdx.x;
  const int sbid = (bid & 7)*512 + (bid >> 3);
  const int w = threadIdx.x >> 6, lane = threadIdx.x & 63;
  const int n = sbid*4 + w;
  const int head = (lane*F)/C;
  const int col  = lane*F;
  const int nb = nbr[n*16 + (lane & 15)];
  float aldn;
  if constexpr (ALSPLIT) aldn = ald[n*2] + ald[n*2+1];
  else                   aldn = ald[n*HEADS + head];
  float e[17];
#pragma unroll
  for (int j=0;j<17;j++){
    const int sj = (j<16) ? __shfl(nb, j) : n;
    float v;
    if constexpr (ALSPLIT) v = als[sj*2] + als[sj*2+1] + aldn;
    else                   v = als[sj*HEADS + head] + aldn;
    e[j] = v > 0.f ? v : 0.2f*v;
  }
  float mx = e[0];
#pragma unroll
  for (int j=1;j<17;j++) mx = fmaxf(mx, e[j]);
  float den = 0.f;
#pragma unroll
  for (int j=0;j<17;j++){ e[j] = expf(e[j]-mx); den += e[j]; }
  float acc[F];
#pragma unroll
  for (int f=0;f<F;f++) acc[f]=0.f;
#pragma unroll
  for (int j=0;j<17;j++){
    const int sj = (j<16) ? __shfl(nb, j) : n;
    const unsigned short* hp = h + (size_t)sj*CT + col;
    if constexpr (F==4){
      const ushort4 v = *(const ushort4*)hp;
      acc[0] += e[j]*bf2f(v.x); acc[1] += e[j]*bf2f(v.y);
      acc[2] += e[j]*bf2f(v.z); acc[3] += e[j]*bf2f(v.w);
    } else {
      const ushort2 v = *(const ushort2*)hp;
      acc[0] += e[j]*bf2f(v.x); acc[1] += e[j]*bf2f(v.y);
    }
  }
  const float inv = 1.f/den;
  if constexpr (F==4){
    ushort4 o;
    o.x = f2bf(gelu_f(acc[0]*inv + bias[col+0]));
    o.y = f2bf(gelu_f(acc[1]*inv + bias[col+1]));
    o.z = f2bf(gelu_f(acc[2]*inv + bias[col+2]));
    o.w = f2bf(gelu_f(acc[3]*inv + bias[col+3]));
    *(ushort4*)(out + (size_t)n*CT + col) = o;
  } else {
    float v0 = gelu_f(acc[0]*inv + bias[col+0]);
    float v1 = gelu_f(acc[1]*inv + bias[col+1]);
    if constexpr (RES){
      const float* xr = xin + (size_t)n*6;
      float r0 = rb[col+0], r1 = rb[col+1];
#pragma unroll
      for (int d=0; d<6; d++){
        const float xv = xr[d];
        r0 += xv*rW[d*128 + col+0];
        r1 += xv*rW[d*128 + col+1];
      }
      v0 += r0; v1 += r1;
    }
    ushort2 o;
    o.x = f2bf(v0); o.y = f2bf(v1);
    *(ushort2*)(out + (size_t)n*CT + col) = o;
  }
}

// ---------------- bf16 MFMA GEMM: A[M,KC]bf16 @ B[KC,NC]bf16, BM=128 BN=64 BK=32;
//                  AL emits per-block attention-logit (partial) sums ----------
template<int KC, int NC, bool BIAS, bool GELU, bool OUTBF16, bool AL, int ALH>
__global__ __launch_bounds__(256) void mgemm_k(const unsigned short* __restrict__ A,
                                               const unsigned short* __restrict__ B,
                                               const float* __restrict__ bias, void* __restrict__ Cout,
                                               const float* __restrict__ asrc, const float* __restrict__ adst,
                                               float* __restrict__ als, float* __restrict__ ald){
  __shared__ unsigned short As[4*128*8];   // [g][row][j]
  __shared__ unsigned short Bs[4*64*8];    // [g][n][j]
  const int t = threadIdx.x, wid = t >> 6, lane = t & 63;
  const int r0 = blockIdx.x*128, c0 = blockIdx.y*64;
  const int lg = lane >> 4, l15 = lane & 15;
  float4v acc[2][4];
#pragma unroll
  for (int rf=0;rf<2;rf++)
#pragma unroll
    for (int cf=0;cf<4;cf++)
#pragma unroll
      for (int r=0;r<4;r++) acc[rf][cf][r] = 0.f;

  const int arow = t >> 1, ak0 = (t & 1)*16;
  const int bk = t >> 3, bn0 = (t & 7)*8;

#pragma unroll 1
  for (int kc=0; kc<KC; kc+=32){
    __syncthreads();
    const unsigned short* Ap = A + (size_t)(r0+arow)*KC + kc + ak0;
    const short8v av0 = *(const short8v*)Ap;
    const short8v av1 = *(const short8v*)(Ap + 8);
    *(short8v*)&As[((ak0>>3)+0)*1024 + arow*8] = av0;
    *(short8v*)&As[((ak0>>3)+1)*1024 + arow*8] = av1;
    const unsigned short* Bp = B + (size_t)(kc+bk)*NC + c0 + bn0;
    const short8v bv = *(const short8v*)Bp;
#pragma unroll
    for (int i=0;i<8;i++) Bs[(bk>>3)*512 + (bn0+i)*8 + (bk&7)] = (unsigned short)bv[i];
    __syncthreads();

    short8v af0 = *(const short8v*)&As[lg*1024 + (wid*32 +  0 + l15)*8];
    short8v af1 = *(const short8v*)&As[lg*1024 + (wid*32 + 16 + l15)*8];
    short8v bf[4];
#pragma unroll
    for (int c=0;c<4;c++) bf[c] = *(const short8v*)&Bs[lg*512 + (c*16 + l15)*8];
#pragma unroll
    for (int cf=0;cf<4;cf++){
      acc[0][cf] = __builtin_amdgcn_mfma_f32_16x16x32_bf16(af0, bf[cf], acc[0][cf], 0,0,0);
      acc[1][cf] = __builtin_amdgcn_mfma_f32_16x16x32_bf16(af1, bf[cf], acc[1][cf], 0,0,0);
    }
  }

  // epilogue: D[row=(lane>>4)*4+r][col=lane&15] per frag [measured: m89]
  float av[4], dv[4];
  if constexpr (AL){
#pragma unroll
    for (int cf=0;cf<4;cf++){
      av[cf] = asrc[c0 + cf*16 + l15];
      dv[cf] = adst[c0 + cf*16 + l15];
    }
  }
#pragma unroll
  for (int rf=0;rf<2;rf++)
#pragma unroll
    for (int r=0;r<4;r++){
      const int row = r0 + wid*32 + rf*16 + lg*4 + r;
      float s = 0.f, d = 0.f;
#pragma unroll
      for (int cf=0;cf<4;cf++){
        const int col = c0 + cf*16 + l15;
        float v = acc[rf][cf][r];
        if constexpr (BIAS) v += bias[col];
        if constexpr (GELU) v = gelu_f(v);
        if constexpr (OUTBF16) ((unsigned short*)Cout)[(size_t)row*NC + col] = f2bf(v);
        else                   ((float*)Cout)[(size_t)row*NC + col] = v;
        if constexpr (AL){ s += v*av[cf]; d += v*dv[cf]; }
      }
      if constexpr (AL){
#pragma unroll
        for (int off=1; off<16; off<<=1){
          s += __shfl_xor(s, off);
          d += __shfl_xor(d, off);
        }
        if (l15 == 0){
          als[row*ALH + (c0>>6)] = s;
          ald[row*ALH + (c0>>6)] = d;
        }
      }
    }
}

// ---------------- fused MLP tail: Y2 = gelu(A@m2W + m2b) [128x64 MFMA], then
//                  out = Y2@m3W + m3b in-register (per-lane partials, 16-lane reduce) ----
__global__ __launch_bounds__(256) void mlp2_k(const unsigned short* __restrict__ A,
                                              const unsigned short* __restrict__ B,
                                              const float* __restrict__ bias2,
                                              const float* __restrict__ W3, const float* __restrict__ b3,
                                              float* __restrict__ out){
  __shared__ unsigned short As[4*128*8];
  __shared__ unsigned short Bs[4*64*8];
  const int t = threadIdx.x, wid = t >> 6, lane = t & 63;
  const int r0 = blockIdx.x*128;
  const int lg = lane >> 4, l15 = lane & 15;
  float4v acc[2][4];
#pragma unroll
  for (int rf=0;rf<2;rf++)
#pragma unroll
    for (int cf=0;cf<4;cf++)
#pragma unroll
      for (int r=0;r<4;r++) acc[rf][cf][r] = 0.f;

  const int arow = t >> 1, ak0 = (t & 1)*16;
  const int bk = t >> 3, bn0 = (t & 7)*8;

#pragma unroll 1
  for (int kc=0; kc<128; kc+=32){
    __syncthreads();
    const unsigned short* Ap = A + (size_t)(r0+arow)*128 + kc + ak0;
    const short8v av0 = *(const short8v*)Ap;
    const short8v av1 = *(const short8v*)(Ap + 8);
    *(short8v*)&As[((ak0>>3)+0)*1024 + arow*8] = av0;
    *(short8v*)&As[((ak0>>3)+1)*1024 + arow*8] = av1;
    const unsigned short* Bp = B + (size_t)(kc+bk)*64 + bn0;
    const short8v bv = *(const short8v*)Bp;
#pragma unroll
    for (int i=0;i<8;i++) Bs[(bk>>3)*512 + (bn0+i)*8 + (bk&7)] = (unsigned short)bv[i];
    __syncthreads();

    short8v af0 = *(const short8v*)&As[lg*1024 + (wid*32 +  0 + l15)*8];
    short8v af1 = *(const short8v*)&As[lg*1024 + (wid*32 + 16 + l15)*8];
    short8v bf[4];
#pragma unroll
    for (int c=0;c<4;c++) bf[c] = *(const short8v*)&Bs[lg*512 + (c*16 + l15)*8];
#pragma unroll
    for (int cf=0;cf<4;cf++){
      acc[0][cf] = __builtin_amdgcn_mfma_f32_16x16x32_bf16(af0, bf[cf], acc[0][cf], 0,0,0);
      acc[1][cf] = __builtin_amdgcn_mfma_f32_16x16x32_bf16(af1, bf[cf], acc[1][cf], 0,0,0);
    }
  }

  // per-lane W3 columns (col = cf*16+l15), bias
  float w3[4][6];
#pragma unroll
  for (int cf=0;cf<4;cf++)
#pragma unroll
    for (int j=0;j<6;j++) w3[cf][j] = W3[(cf*16 + l15)*6 + j];
  float b2l[4];
#pragma unroll
  for (int cf=0;cf<4;cf++) b2l[cf] = bias2[cf*16 + l15];

#pragma unroll
  for (int rf=0;rf<2;rf++)
#pragma unroll
    for (int r=0;r<4;r++){
      const int row = r0 + wid*32 + rf*16 + lg*4 + r;
      float p[6] = {0.f,0.f,0.f,0.f,0.f,0.f};
#pragma unroll
      for (int cf=0;cf<4;cf++){
        float v = gelu_f(acc[rf][cf][r] + b2l[cf]);
        const float vv = bf2f(f2bf(v));   // preserve previous bf16 quantization point
#pragma unroll
        for (int j=0;j<6;j++) p[j] += vv*w3[cf][j];
      }
#pragma unroll
      for (int off=1; off<16; off<<=1)
#pragma unroll
        for (int j=0;j<6;j++) p[j] += __shfl_xor(p[j], off);
      if (l15 == 0){
#pragma unroll
        for (int j=0;j<6;j++) out[(size_t)row*6 + j] = p[j] + b3[j];
      }
    }
}

extern "C" void kernel_launch(void* const* d_in, const int* in_sizes, int n_in,
                              void* d_out, int out_size, void* d_ws, size_t ws_size,
                              hipStream_t stream){
  (void)in_sizes; (void)n_in; (void)out_size; (void)ws_size;
  const float* x      = (const float*)d_in[0];
  const float* W1     = (const float*)d_in[1];
  const float* a_src1 = (const float*)d_in[2];
  const float* a_dst1 = (const float*)d_in[3];
  const float* b1     = (const float*)d_in[4];
  const float* W2     = (const float*)d_in[5];
  const float* a_src2 = (const float*)d_in[6];
  const float* a_dst2 = (const float*)d_in[7];
  const float* b2     = (const float*)d_in[8];
  const float* W3     = (const float*)d_in[9];
  const float* a_src3 = (const float*)d_in[10];
  const float* a_dst3 = (const float*)d_in[11];
  const float* b3     = (const float*)d_in[12];
  const float* res_W  = (const float*)d_in[13];
  const float* res_b  = (const float*)d_in[14];
  const float* m1_W   = (const float*)d_in[15];
  const float* m1_b   = (const float*)d_in[16];
  const float* m2_W   = (const float*)d_in[17];
  const float* m2_b   = (const float*)d_in[18];
  const float* m3_W   = (const float*)d_in[19];
  const float* m3_b   = (const float*)d_in[20];
  float* out = (float*)d_out;

  char* wsb = (char*)d_ws;
  int*            nbr   = (int*)wsb;                                 // 1 MB
  unsigned short* HB256 = (unsigned short*)(wsb + (1u<<20));         // 8 MB bf16 [NN,256]
  unsigned short* YB256 = (unsigned short*)(wsb + (9u<<20));         // 8 MB bf16 [NN,256]
  unsigned short* HB128 = (unsigned short*)(wsb + (17u<<20));        // 4 MB bf16 [NN,128]
  unsigned short* YB128 = (unsigned short*)(wsb + (21u<<20));        // 4 MB bf16 [NN,128]
  unsigned short* HM128 = (unsigned short*)(wsb + (25u<<20));        // 4 MB bf16 [NN,128]
  float*          ALS   = (float*)(wsb + (31u<<20));                 // 256 KB
  float*          ALD   = ALS + NN*4;                                // 256 KB
  float4*         PA    = (float4*)(wsb + (31u<<20) + (512u<<10));   // 256 KB
  float4*         PB    = PA + NN;                                   // 256 KB
  uint4*          PH    = (uint4*)(wsb + (32u<<20));                 // 256 KB
  unsigned short* Wb    = (unsigned short*)(wsb + (32u<<20) + (512u<<10)); // 240 KB
  unsigned short* W2b = Wb;
  unsigned short* W3b = Wb + 65536;
  unsigned short* m1b = Wb + 98304;
  unsigned short* m2b = Wb + 114688;

  prep_k<<<NN/256 + 480, 256, 0, stream>>>(x, PA, PB, PH, W2, W3, m1_W, m2_W, Wb);
  knn_k<<<NN/4, 256, 0, stream>>>(PH, PA, PB, nbr);

  // GAT layer 1: 6 -> 4x64 (al fused into GEMM), bf16 H
  gemm_in6<<<NN/4, 256, 0, stream>>>(x, W1, a_src1, a_dst1, HB256, ALS, ALD);
  agg_k<4,64,false,false><<<NN/4, 256, 0, stream>>>(HB256, ALS, ALD, nbr, b1, YB256, nullptr, nullptr, nullptr);

  // GAT layer 2: 256 -> 4x64 (attention logits fused into GEMM epilogue)
  mgemm_k<256,256,false,false,true,true,4><<<dim3(128,4), 256, 0, stream>>>(
      YB256, W2b, nullptr, HB256, a_src2, a_dst2, ALS, ALD);
  agg_k<4,64,false,false><<<NN/4, 256, 0, stream>>>(HB256, ALS, ALD, nbr, b2, YB256, nullptr, nullptr, nullptr);

  // GAT layer 3: 256 -> 1x128; split attention logits fused into GEMM epilogue
  mgemm_k<256,128,false,false,true,true,2><<<dim3(128,2), 256, 0, stream>>>(
      YB256, W3b, nullptr, HB128, a_src3, a_dst3, ALS, ALD);
  agg_k<1,128,true,true><<<NN/4, 256, 0, stream>>>(HB128, ALS, ALD, nbr, b3, YB128, x, res_W, res_b);

  // MLP: m1 MFMA, then fused m2+m3
  mgemm_k<128,128,true,true,true,false,1><<<dim3(128,2), 256, 0, stream>>>(
      YB128, m1b, m1_b, HM128, nullptr, nullptr, nullptr, nullptr);
  mlp2_k<<<128, 256, 0, stream>>>(HM128, m2b, m2_b, m3_W, m3_b, out);
}

// Round 24
// 172.635 us; speedup vs baseline: 1.2294x; 1.0088x over previous
//
#include <hip/hip_runtime.h>
#include <math.h>

#define NN 16384      // B*N total nodes
#define NPB 4096      // nodes per batch
#define KCAP 128      // survivor capacity per query (expected ~30 with guard)
#define TS 1024       // kNN candidate tile size (4 tiles -> 3 in-loop barriers)
#define GUARD 0.25f   // d2-space guard: >= 2x worst f16-rounding error + trunc slack

typedef __attribute__((ext_vector_type(8))) short short8v;
typedef __attribute__((ext_vector_type(4))) float float4v;
typedef __attribute__((ext_vector_type(2))) _Float16 half2v;

#if defined(__has_builtin)
#if __has_builtin(__builtin_amdgcn_fdot2)
#define HAS_FDOT2 1
#endif
#endif

#ifdef HAS_FDOT2
#define FDOT2(a,b,c) __builtin_amdgcn_fdot2((a),(b),(c),false)
#else
__device__ __forceinline__ float FDOT2(half2v a, half2v b, float c){
  return c + (float)a[0]*(float)b[0] + (float)a[1]*(float)b[1];
}
#endif

__device__ __forceinline__ float gelu_f(float v){
  return 0.5f*v*(1.0f+erff(v*0.70710678118654752440f));
}

// f32 -> bf16 bits, round-to-nearest-even
__device__ __forceinline__ unsigned short f2bf(float v){
  union{float f; unsigned u;} c; c.f = v;
  const unsigned r = c.u + 0x7FFFu + ((c.u >> 16) & 1u);
  return (unsigned short)(r >> 16);
}
__device__ __forceinline__ float bf2f(unsigned short b){
  return __uint_as_float(((unsigned)b) << 16);
}

// monotone float->uint map: order-preserving for all finite values
__device__ __forceinline__ unsigned fmap(float d2){
  unsigned u = __float_as_uint(d2);
  return u ^ ((unsigned)((int)u >> 31) | 0x80000000u);
}

// canonical exact distance key (same expression everywhere -> identical bits)
__device__ __forceinline__ unsigned dkey(const float4 qa, const float4 qb, const float sqn,
                                         const float4 a, const float4 b){
  const float dot = qa.x*a.x + qa.y*a.y + qa.z*a.z + qa.w*a.w + qb.x*b.x + qb.y*b.y;
  const float d2 = sqn + b.z - 2.0f*dot;
  return fmap(d2);
}

// ascending-by-lane bitonic sort of one u64 per lane across the 64-lane wave
__device__ __forceinline__ unsigned long long bsort64(unsigned long long v, int lane){
#pragma unroll
  for (int k=2;k<=64;k<<=1){
#pragma unroll
    for (int j=k>>1;j>0;j>>=1){
      const unsigned long long o = __shfl_xor(v, j);
      const bool keepMin = ((lane & k) == 0) == ((lane & j) == 0);
      const unsigned long long mn = v < o ? v : o;
      const unsigned long long mx = v < o ? o : v;
      v = keepMin ? mn : mx;
    }
  }
  return v;
}

// ascending-by-lane bitonic sort of one u32 per lane
__device__ __forceinline__ unsigned bsort32(unsigned v, int lane){
#pragma unroll
  for (int k=2;k<=64;k<<=1){
#pragma unroll
    for (int j=k>>1;j>0;j>>=1){
      const unsigned o = __shfl_xor(v, j);
      const bool keepMin = ((lane & k) == 0) == ((lane & j) == 0);
      const unsigned mn = v < o ? v : o;
      const unsigned mx = v < o ? o : v;
      v = keepMin ? mn : mx;
    }
  }
  return v;
}

// ---------------- merged prep: blocks 0..63 pack x -> PA/PB/PH; blocks 64.. convert weights ----
__global__ __launch_bounds__(256) void prep_k(const float* __restrict__ x,
                                              float4* __restrict__ PA, float4* __restrict__ PB,
                                              uint4* __restrict__ PH,
                                              const float* __restrict__ W2, const float* __restrict__ W3,
                                              const float* __restrict__ m1W, const float* __restrict__ m2W,
                                              unsigned short* __restrict__ o){
  if (blockIdx.x < NN/256){
    const int n = blockIdx.x*256 + threadIdx.x;
    const float* xr = x + (size_t)n*6;
    const float x0=xr[0],x1=xr[1],x2=xr[2],x3=xr[3],x4=xr[4],x5=xr[5];
    const float sq = x0*x0+x1*x1+x2*x2+x3*x3+x4*x4+x5*x5;
    PA[n] = make_float4(x0,x1,x2,x3);
    PB[n] = make_float4(x4,x5,sq,0.f);
    half2v h01 = {(_Float16)x0, (_Float16)x1};
    half2v h23 = {(_Float16)x2, (_Float16)x3};
    half2v h45 = {(_Float16)x4, (_Float16)x5};
    uint4 ph;
    ph.x = __builtin_bit_cast(unsigned, h01);
    ph.y = __builtin_bit_cast(unsigned, h23);
    ph.z = __builtin_bit_cast(unsigned, h45);
    ph.w = __float_as_uint(sq);
    PH[n] = ph;
  } else {
    const int i = (blockIdx.x - NN/256)*256 + threadIdx.x;   // 122880 total
    float v;
    if (i < 65536)       v = W2[i];
    else if (i < 98304)  v = W3[i-65536];
    else if (i < 114688) v = m1W[i-98304];
    else                 v = m2W[i-114688];
    o[i] = f2bf(v);
  }
}

// ---------------- kNN v18: 512-thread blocks (8 queries/block) — same per-wave structure,
//                  same LDS tiles now shared by 8 waves -> 2x waves/CU at 4 blocks/CU
//                  (40960 B x 4 = 160 KB exactly). kp[32]/wave unchanged (SROA-safe). ----------
__global__ void knn_k(const uint4* __restrict__ PH, const float4* __restrict__ PA,
                      const float4* __restrict__ PB, int* __restrict__ nbr){
  __shared__ uint2 C1[2][TS];              // 16 KB {h01,h23}
  __shared__ uint2 C2[2][TS];              // 16 KB {h45,sq}
  __shared__ unsigned skey[8][KCAP];       // 4 KB
  __shared__ unsigned sslot[8][KCAP];      // 4 KB
  const int t = threadIdx.x, w = t >> 6, lane = t & 63;
  const int n = blockIdx.x*8 + w;
  const int base = n & ~(NPB-1);
  const uint4 qh = PH[n];
  const half2v q01 = __builtin_bit_cast(half2v, qh.x);
  const half2v q23 = __builtin_bit_cast(half2v, qh.y);
  const half2v q45 = __builtin_bit_cast(half2v, qh.z);
  const float sqn = __uint_as_float(qh.w);
  const int selfslot = n - base;

  // stage tile 0 (1024 entries, 2 per thread)
  {
#pragma unroll
    for (int u=0;u<2;u++){
      const uint4 c = PH[base + u*512 + t];
      C1[0][u*512+t] = make_uint2(c.x, c.y);
      C2[0][u*512+t] = make_uint2(c.z, c.w);
    }
  }
  __syncthreads();

  unsigned kp[32];
  float minf = 3e38f;
#pragma unroll
  for (int tile=0; tile<NPB/TS; ++tile){
    const int buf = tile & 1;
    // issue next tile's global loads BEFORE compute (latency hides under distance loop)
    uint4 n0, n1;
    if (tile < NPB/TS-1){
      n0 = PH[base + (tile+1)*TS +   0 + t];
      n1 = PH[base + (tile+1)*TS + 512 + t];
    }
    unsigned lo = 0;
#pragma unroll
    for (int it=0; it<TS/64; ++it){
      const int s = it*64 + lane;
      const uint2 c1 = C1[buf][s];
      const uint2 c2 = C2[buf][s];
      const float dot = FDOT2(q01, __builtin_bit_cast(half2v, c1.x),
                        FDOT2(q23, __builtin_bit_cast(half2v, c1.y),
                        FDOT2(q45, __builtin_bit_cast(half2v, c2.x), 0.f)));
      float d2 = fmaf(-2.f, dot, sqn + __uint_as_float(c2.y));
      d2 = fmaxf(d2, 0.f);
      if (tile*TS + s == selfslot) d2 = 3e38f;   // exclude self
      minf = fminf(minf, d2);
      const unsigned u16 = __float_as_uint(d2) >> 16;   // trunc: monotone for >=0
      if ((it & 1) == 0) lo = u16;
      else               kp[(tile*(TS/64)+it)>>1] = lo | (u16 << 16);
    }
    if (tile < NPB/TS-1){
      C1[buf^1][      t] = make_uint2(n0.x, n0.y);
      C2[buf^1][      t] = make_uint2(n0.z, n0.w);
      C1[buf^1][512 + t] = make_uint2(n1.x, n1.y);
      C2[buf^1][512 + t] = make_uint2(n1.z, n1.w);
      __syncthreads();
    }
  }

  // pivot: 16th smallest lane-min (floats >=0 -> u32-bit order == float order)
  unsigned T = bsort32(__float_as_uint(minf), lane);
  T = __shfl(T, 15);
  const float TG = __uint_as_float(T) + GUARD;
  const unsigned T16 = __float_as_uint(TG) >> 16;

  // compact survivors (trunc(d2~) <= trunc(TG) -> superset of exact top-16)
  // q = tile*16 + it (16 its/tile at TS=1024); slot = (q>>4)*TS + (q&15)*64 + lane
  int cnt = 0;
#pragma unroll
  for (int q=0; q<64; ++q){
    const unsigned k16 = (kp[q>>1] >> ((q&1)*16)) & 0xFFFFu;
    const bool p = k16 <= T16;
    const unsigned long long bb = __ballot(p);
    if (p){
      const int pos = cnt + (int)__popcll(bb & ((1ull << lane) - 1ull));
      if (pos < KCAP) sslot[w][pos] = (unsigned)((q>>4)*TS + (q&15)*64 + lane);
    }
    cnt += (int)__popcll(bb);
  }
  if (cnt > KCAP) cnt = KCAP;

  // recompute EXACT keys for survivors (canonical fp32 dkey from global PA/PB)
  for (int i=lane; i<cnt; i+=64){
    const int slot = (int)sslot[w][i];
    const float4 qa = PA[n];
    const float4 qb = PB[n];
    skey[w][i] = dkey(qa, qb, qb.z, PA[base+slot], PB[base+slot]);
  }

  // final: exact top-16 over survivors (u64 = key||slot, ascending, slot tie-break)
  unsigned long long vbest;
  {
    unsigned long long v = ~0ull;
    if (lane < cnt) v = ((unsigned long long)skey[w][lane] << 32) | sslot[w][lane];
    vbest = bsort64(v, lane);
  }
  for (int c=1; c*64 < cnt; ++c){
    const int i = c*64 + lane;
    unsigned long long v = ~0ull;
    if (i < cnt) v = ((unsigned long long)skey[w][i] << 32) | sslot[w][i];
    v = bsort64(v, lane);
    const unsigned long long r = __shfl(v, 63-lane);
    vbest = vbest < r ? vbest : r;
#pragma unroll
    for (int j=32;j>0;j>>=1){
      const unsigned long long o = __shfl_xor(vbest, j);
      const bool keepMin = (lane & j) == 0;
      const unsigned long long mn = vbest < o ? vbest : o;
      const unsigned long long mx = vbest < o ? o : vbest;
      vbest = keepMin ? mn : mx;
    }
  }
  if (lane < 16) nbr[n*16 + lane] = base + (int)(vbest & 0xFFFFFFFFull);
}

// ---------------- layer-1 GEMM + fused attention logits -> bf16 H ----------------
__global__ __launch_bounds__(256) void gemm_in6(const float* __restrict__ x, const float* __restrict__ W,
                                                const float* __restrict__ asrc, const float* __restrict__ adst,
                                                unsigned short* __restrict__ h,
                                                float* __restrict__ als, float* __restrict__ ald){
  const int t = blockIdx.x*256 + threadIdx.x;  // over NN*64
  const int n = t >> 6, cg = t & 63;
  const float* xr = x + n*6;
  float xv[6];
#pragma unroll
  for (int d=0; d<6; d++) xv[d] = xr[d];
  float4 acc = make_float4(0.f,0.f,0.f,0.f);
#pragma unroll
  for (int d=0; d<6; d++){
    const float4 wv = *(const float4*)(W + d*256 + cg*4);
    acc.x += xv[d]*wv.x; acc.y += xv[d]*wv.y; acc.z += xv[d]*wv.z; acc.w += xv[d]*wv.w;
  }
  ushort4 o;
  o.x = f2bf(acc.x); o.y = f2bf(acc.y); o.z = f2bf(acc.z); o.w = f2bf(acc.w);
  *(ushort4*)(h + (size_t)n*256 + cg*4) = o;

  const int head = cg >> 4;
  const float4 av = *(const float4*)(asrc + head*64 + (cg&15)*4);
  const float4 dv = *(const float4*)(adst + head*64 + (cg&15)*4);
  float s = acc.x*av.x + acc.y*av.y + acc.z*av.z + acc.w*av.w;
  float d = acc.x*dv.x + acc.y*dv.y + acc.z*dv.z + acc.w*dv.w;
#pragma unroll
  for (int off=1; off<16; off<<=1){
    s += __shfl_xor(s, off);
    d += __shfl_xor(d, off);
  }
  if ((cg & 15) == 0){
    als[n*4 + head] = s;
    ald[n*4 + head] = d;
  }
}

// ---------------- GAT aggregation (bf16 gather) -> bf16 output rows;
//                  XCD-swizzled blocks; ALSPLIT sums 2 partial logit slots (layer 3);
//                  RES fuses x@res_W + res_b (layer 3) ----------------
template<int HEADS, int C, bool RES, bool ALSPLIT>
__global__ __launch_bounds__(256) void agg_k(const unsigned short* __restrict__ h,
                                             const float* __restrict__ als, const float* __restrict__ ald,
                                             const int* __restrict__ nbr,
                                             const float* __restrict__ bias, unsigned short* __restrict__ out,
                                             const float* __restrict__ xin, const float* __restrict__ rW,
                                             const float* __restrict__ rb){
  constexpr int CT = HEADS*C;
  constexpr int F  = CT/64;
  const int bid = blockIdx.x;
  const int sbid = (bid & 7)*512 + (bid >> 3);
  const int w = threadIdx.x >> 6, lane = threadIdx.x & 63;
  const int n = sbid*4 + w;
  const int head = (lane*F)/C;
  const int col  = lane*F;
  const int nb = nbr[n*16 + (lane & 15)];
  float aldn;
  if constexpr (ALSPLIT) aldn = ald[n*2] + ald[n*2+1];
  else                   aldn = ald[n*HEADS + head];
  float e[17];
#pragma unroll
  for (int j=0;j<17;j++){
    const int sj = (j<16) ? __shfl(nb, j) : n;
    float v;
    if constexpr (ALSPLIT) v = als[sj*2] + als[sj*2+1] + aldn;
    else                   v = als[sj*HEADS + head] + aldn;
    e[j] = v > 0.f ? v : 0.2f*v;
  }
  float mx = e[0];
#pragma unroll
  for (int j=1;j<17;j++) mx = fmaxf(mx, e[j]);
  float den = 0.f;
#pragma unroll
  for (int j=0;j<17;j++){ e[j] = expf(e[j]-mx); den += e[j]; }
  float acc[F];
#pragma unroll
  for (int f=0;f<F;f++) acc[f]=0.f;
#pragma unroll
  for (int j=0;j<17;j++){
    const int sj = (j<16) ? __shfl(nb, j) : n;
    const unsigned short* hp = h + (size_t)sj*CT + col;
    if constexpr (F==4){
      const ushort4 v = *(const ushort4*)hp;
      acc[0] += e[j]*bf2f(v.x); acc[1] += e[j]*bf2f(v.y);
      acc[2] += e[j]*bf2f(v.z); acc[3] += e[j]*bf2f(v.w);
    } else {
      const ushort2 v = *(const ushort2*)hp;
      acc[0] += e[j]*bf2f(v.x); acc[1] += e[j]*bf2f(v.y);
    }
  }
  const float inv = 1.f/den;
  if constexpr (F==4){
    ushort4 o;
    o.x = f2bf(gelu_f(acc[0]*inv + bias[col+0]));
    o.y = f2bf(gelu_f(acc[1]*inv + bias[col+1]));
    o.z = f2bf(gelu_f(acc[2]*inv + bias[col+2]));
    o.w = f2bf(gelu_f(acc[3]*inv + bias[col+3]));
    *(ushort4*)(out + (size_t)n*CT + col) = o;
  } else {
    float v0 = gelu_f(acc[0]*inv + bias[col+0]);
    float v1 = gelu_f(acc[1]*inv + bias[col+1]);
    if constexpr (RES){
      const float* xr = xin + (size_t)n*6;
      float r0 = rb[col+0], r1 = rb[col+1];
#pragma unroll
      for (int d=0; d<6; d++){
        const float xv = xr[d];
        r0 += xv*rW[d*128 + col+0];
        r1 += xv*rW[d*128 + col+1];
      }
      v0 += r0; v1 += r1;
    }
    ushort2 o;
    o.x = f2bf(v0); o.y = f2bf(v1);
    *(ushort2*)(out + (size_t)n*CT + col) = o;
  }
}

// ---------------- bf16 MFMA GEMM: A[M,KC]bf16 @ B[KC,NC]bf16, BM=128 BN=64 BK=32;
//                  AL emits per-block attention-logit (partial) sums ----------
template<int KC, int NC, bool BIAS, bool GELU, bool OUTBF16, bool AL, int ALH>
__global__ __launch_bounds__(256) void mgemm_k(const unsigned short* __restrict__ A,
                                               const unsigned short* __restrict__ B,
                                               const float* __restrict__ bias, void* __restrict__ Cout,
                                               const float* __restrict__ asrc, const float* __restrict__ adst,
                                               float* __restrict__ als, float* __restrict__ ald){
  __shared__ unsigned short As[4*128*8];   // [g][row][j]
  __shared__ unsigned short Bs[4*64*8];    // [g][n][j]
  const int t = threadIdx.x, wid = t >> 6, lane = t & 63;
  const int r0 = blockIdx.x*128, c0 = blockIdx.y*64;
  const int lg = lane >> 4, l15 = lane & 15;
  float4v acc[2][4];
#pragma unroll
  for (int rf=0;rf<2;rf++)
#pragma unroll
    for (int cf=0;cf<4;cf++)
#pragma unroll
      for (int r=0;r<4;r++) acc[rf][cf][r] = 0.f;

  const int arow = t >> 1, ak0 = (t & 1)*16;
  const int bk = t >> 3, bn0 = (t & 7)*8;

#pragma unroll 1
  for (int kc=0; kc<KC; kc+=32){
    __syncthreads();
    const unsigned short* Ap = A + (size_t)(r0+arow)*KC + kc + ak0;
    const short8v av0 = *(const short8v*)Ap;
    const short8v av1 = *(const short8v*)(Ap + 8);
    *(short8v*)&As[((ak0>>3)+0)*1024 + arow*8] = av0;
    *(short8v*)&As[((ak0>>3)+1)*1024 + arow*8] = av1;
    const unsigned short* Bp = B + (size_t)(kc+bk)*NC + c0 + bn0;
    const short8v bv = *(const short8v*)Bp;
#pragma unroll
    for (int i=0;i<8;i++) Bs[(bk>>3)*512 + (bn0+i)*8 + (bk&7)] = (unsigned short)bv[i];
    __syncthreads();

    short8v af0 = *(const short8v*)&As[lg*1024 + (wid*32 +  0 + l15)*8];
    short8v af1 = *(const short8v*)&As[lg*1024 + (wid*32 + 16 + l15)*8];
    short8v bf[4];
#pragma unroll
    for (int c=0;c<4;c++) bf[c] = *(const short8v*)&Bs[lg*512 + (c*16 + l15)*8];
#pragma unroll
    for (int cf=0;cf<4;cf++){
      acc[0][cf] = __builtin_amdgcn_mfma_f32_16x16x32_bf16(af0, bf[cf], acc[0][cf], 0,0,0);
      acc[1][cf] = __builtin_amdgcn_mfma_f32_16x16x32_bf16(af1, bf[cf], acc[1][cf], 0,0,0);
    }
  }

  // epilogue: D[row=(lane>>4)*4+r][col=lane&15] per frag [measured: m89]
  float av[4], dv[4];
  if constexpr (AL){
#pragma unroll
    for (int cf=0;cf<4;cf++){
      av[cf] = asrc[c0 + cf*16 + l15];
      dv[cf] = adst[c0 + cf*16 + l15];
    }
  }
#pragma unroll
  for (int rf=0;rf<2;rf++)
#pragma unroll
    for (int r=0;r<4;r++){
      const int row = r0 + wid*32 + rf*16 + lg*4 + r;
      float s = 0.f, d = 0.f;
#pragma unroll
      for (int cf=0;cf<4;cf++){
        const int col = c0 + cf*16 + l15;
        float v = acc[rf][cf][r];
        if constexpr (BIAS) v += bias[col];
        if constexpr (GELU) v = gelu_f(v);
        if constexpr (OUTBF16) ((unsigned short*)Cout)[(size_t)row*NC + col] = f2bf(v);
        else                   ((float*)Cout)[(size_t)row*NC + col] = v;
        if constexpr (AL){ s += v*av[cf]; d += v*dv[cf]; }
      }
      if constexpr (AL){
#pragma unroll
        for (int off=1; off<16; off<<=1){
          s += __shfl_xor(s, off);
          d += __shfl_xor(d, off);
        }
        if (l15 == 0){
          als[row*ALH + (c0>>6)] = s;
          ald[row*ALH + (c0>>6)] = d;
        }
      }
    }
}

// ---------------- fused MLP tail: Y2 = gelu(A@m2W + m2b) [128x64 MFMA], then
//                  out = Y2@m3W + m3b in-register (per-lane partials, 16-lane reduce) ----
__global__ __launch_bounds__(256) void mlp2_k(const unsigned short* __restrict__ A,
                                              const unsigned short* __restrict__ B,
                                              const float* __restrict__ bias2,
                                              const float* __restrict__ W3, const float* __restrict__ b3,
                                              float* __restrict__ out){
  __shared__ unsigned short As[4*128*8];
  __shared__ unsigned short Bs[4*64*8];
  const int t = threadIdx.x, wid = t >> 6, lane = t & 63;
  const int r0 = blockIdx.x*128;
  const int lg = lane >> 4, l15 = lane & 15;
  float4v acc[2][4];
#pragma unroll
  for (int rf=0;rf<2;rf++)
#pragma unroll
    for (int cf=0;cf<4;cf++)
#pragma unroll
      for (int r=0;r<4;r++) acc[rf][cf][r] = 0.f;

  const int arow = t >> 1, ak0 = (t & 1)*16;
  const int bk = t >> 3, bn0 = (t & 7)*8;

#pragma unroll 1
  for (int kc=0; kc<128; kc+=32){
    __syncthreads();
    const unsigned short* Ap = A + (size_t)(r0+arow)*128 + kc + ak0;
    const short8v av0 = *(const short8v*)Ap;
    const short8v av1 = *(const short8v*)(Ap + 8);
    *(short8v*)&As[((ak0>>3)+0)*1024 + arow*8] = av0;
    *(short8v*)&As[((ak0>>3)+1)*1024 + arow*8] = av1;
    const unsigned short* Bp = B + (size_t)(kc+bk)*64 + bn0;
    const short8v bv = *(const short8v*)Bp;
#pragma unroll
    for (int i=0;i<8;i++) Bs[(bk>>3)*512 + (bn0+i)*8 + (bk&7)] = (unsigned short)bv[i];
    __syncthreads();

    short8v af0 = *(const short8v*)&As[lg*1024 + (wid*32 +  0 + l15)*8];
    short8v af1 = *(const short8v*)&As[lg*1024 + (wid*32 + 16 + l15)*8];
    short8v bf[4];
#pragma unroll
    for (int c=0;c<4;c++) bf[c] = *(const short8v*)&Bs[lg*512 + (c*16 + l15)*8];
#pragma unroll
    for (int cf=0;cf<4;cf++){
      acc[0][cf] = __builtin_amdgcn_mfma_f32_16x16x32_bf16(af0, bf[cf], acc[0][cf], 0,0,0);
      acc[1][cf] = __builtin_amdgcn_mfma_f32_16x16x32_bf16(af1, bf[cf], acc[1][cf], 0,0,0);
    }
  }

  // per-lane W3 columns (col = cf*16+l15), bias
  float w3[4][6];
#pragma unroll
  for (int cf=0;cf<4;cf++)
#pragma unroll
    for (int j=0;j<6;j++) w3[cf][j] = W3[(cf*16 + l15)*6 + j];
  float b2l[4];
#pragma unroll
  for (int cf=0;cf<4;cf++) b2l[cf] = bias2[cf*16 + l15];

#pragma unroll
  for (int rf=0;rf<2;rf++)
#pragma unroll
    for (int r=0;r<4;r++){
      const int row = r0 + wid*32 + rf*16 + lg*4 + r;
      float p[6] = {0.f,0.f,0.f,0.f,0.f,0.f};
#pragma unroll
      for (int cf=0;cf<4;cf++){
        float v = gelu_f(acc[rf][cf][r] + b2l[cf]);
        const float vv = bf2f(f2bf(v));   // preserve previous bf16 quantization point
#pragma unroll
        for (int j=0;j<6;j++) p[j] += vv*w3[cf][j];
      }
#pragma unroll
      for (int off=1; off<16; off<<=1)
#pragma unroll
        for (int j=0;j<6;j++) p[j] += __shfl_xor(p[j], off);
      if (l15 == 0){
#pragma unroll
        for (int j=0;j<6;j++) out[(size_t)row*6 + j] = p[j] + b3[j];
      }
    }
}

extern "C" void kernel_launch(void* const* d_in, const int* in_sizes, int n_in,
                              void* d_out, int out_size, void* d_ws, size_t ws_size,
                              hipStream_t stream){
  (void)in_sizes; (void)n_in; (void)out_size; (void)ws_size;
  const float* x      = (const float*)d_in[0];
  const float* W1     = (const float*)d_in[1];
  const float* a_src1 = (const float*)d_in[2];
  const float* a_dst1 = (const float*)d_in[3];
  const float* b1     = (const float*)d_in[4];
  const float* W2     = (const float*)d_in[5];
  const float* a_src2 = (const float*)d_in[6];
  const float* a_dst2 = (const float*)d_in[7];
  const float* b2     = (const float*)d_in[8];
  const float* W3     = (const float*)d_in[9];
  const float* a_src3 = (const float*)d_in[10];
  const float* a_dst3 = (const float*)d_in[11];
  const float* b3     = (const float*)d_in[12];
  const float* res_W  = (const float*)d_in[13];
  const float* res_b  = (const float*)d_in[14];
  const float* m1_W   = (const float*)d_in[15];
  const float* m1_b   = (const float*)d_in[16];
  const float* m2_W   = (const float*)d_in[17];
  const float* m2_b   = (const float*)d_in[18];
  const float* m3_W   = (const float*)d_in[19];
  const float* m3_b   = (const float*)d_in[20];
  float* out = (float*)d_out;

  char* wsb = (char*)d_ws;
  int*            nbr   = (int*)wsb;                                 // 1 MB
  unsigned short* HB256 = (unsigned short*)(wsb + (1u<<20));         // 8 MB bf16 [NN,256]
  unsigned short* YB256 = (unsigned short*)(wsb + (9u<<20));         // 8 MB bf16 [NN,256]
  unsigned short* HB128 = (unsigned short*)(wsb + (17u<<20));        // 4 MB bf16 [NN,128]
  unsigned short* YB128 = (unsigned short*)(wsb + (21u<<20));        // 4 MB bf16 [NN,128]
  unsigned short* HM128 = (unsigned short*)(wsb + (25u<<20));        // 4 MB bf16 [NN,128]
  float*          ALS   = (float*)(wsb + (31u<<20));                 // 256 KB
  float*          ALD   = ALS + NN*4;                                // 256 KB
  float4*         PA    = (float4*)(wsb + (31u<<20) + (512u<<10));   // 256 KB
  float4*         PB    = PA + NN;                                   // 256 KB
  uint4*          PH    = (uint4*)(wsb + (32u<<20));                 // 256 KB
  unsigned short* Wb    = (unsigned short*)(wsb + (32u<<20) + (512u<<10)); // 240 KB
  unsigned short* W2b = Wb;
  unsigned short* W3b = Wb + 65536;
  unsigned short* m1b = Wb + 98304;
  unsigned short* m2b = Wb + 114688;

  prep_k<<<NN/256 + 480, 256, 0, stream>>>(x, PA, PB, PH, W2, W3, m1_W, m2_W, Wb);
  knn_k<<<NN/8, 512, 0, stream>>>(PH, PA, PB, nbr);

  // GAT layer 1: 6 -> 4x64 (al fused into GEMM), bf16 H
  gemm_in6<<<NN/4, 256, 0, stream>>>(x, W1, a_src1, a_dst1, HB256, ALS, ALD);
  agg_k<4,64,false,false><<<NN/4, 256, 0, stream>>>(HB256, ALS, ALD, nbr, b1, YB256, nullptr, nullptr, nullptr);

  // GAT layer 2: 256 -> 4x64 (attention logits fused into GEMM epilogue)
  mgemm_k<256,256,false,false,true,true,4><<<dim3(128,4), 256, 0, stream>>>(
      YB256, W2b, nullptr, HB256, a_src2, a_dst2, ALS, ALD);
  agg_k<4,64,false,false><<<NN/4, 256, 0, stream>>>(HB256, ALS, ALD, nbr, b2, YB256, nullptr, nullptr, nullptr);

  // GAT layer 3: 256 -> 1x128; split attention logits fused into GEMM epilogue
  mgemm_k<256,128,false,false,true,true,2><<<dim3(128,2), 256, 0, stream>>>(
      YB256, W3b, nullptr, HB128, a_src3, a_dst3, ALS, ALD);
  agg_k<1,128,true,true><<<NN/4, 256, 0, stream>>>(HB128, ALS, ALD, nbr, b3, YB128, x, res_W, res_b);

  // MLP: m1 MFMA, then fused m2+m3
  mgemm_k<128,128,true,true,true,false,1><<<dim3(128,2), 256, 0, stream>>>(
      YB128, m1b, m1_b, HM128, nullptr, nullptr, nullptr, nullptr);
  mlp2_k<<<128, 256, 0, stream>>>(HM128, m2b, m2_b, m3_W, m3_b, out);
}